// Round 14
// baseline (407.974 us; speedup 1.0000x reference)
//
#include <hip/hip_runtime.h>
#include <hip/hip_bf16.h>
#include <math.h>

#define EPS 1e-5f

typedef __hip_bfloat16 bf16;
typedef short short8 __attribute__((ext_vector_type(8)));
typedef float float4v __attribute__((ext_vector_type(4)));

__device__ __forceinline__ float toF(float v) { return v; }
__device__ __forceinline__ float toF(bf16 v) { return __bfloat162float(v); }
__device__ __forceinline__ void stF(float* p, float v) { *p = v; }
__device__ __forceinline__ void stF(bf16* p, float v) { *p = __float2bfloat16(v); }
__device__ __forceinline__ short f2bs(float v) {
    bf16 b = __float2bfloat16(v);
    return *reinterpret_cast<short*>(&b);
}
__device__ __forceinline__ float bs2f(short s) {
    unsigned u = ((unsigned)(unsigned short)s) << 16;
    return __uint_as_float(u);
}

// direct global->LDS DMA, 16B per lane. LDS dest: wave-uniform base + lane*16.
__device__ __forceinline__ void gload_lds16(const short* g, short* l) {
    __builtin_amdgcn_global_load_lds(
        (const __attribute__((address_space(1))) unsigned int*)g,
        (__attribute__((address_space(3))) unsigned int*)l, 16, 0, 0);
}

// BN finalize formula (identical to the removed bn_finalize_kernel)
__device__ __forceinline__ void bn_fin(float sum, float sq, float g, float b, float cnt,
                                       float& scale, float& shift) {
    float mean = sum / cnt;
    float var = fmaxf(sq / cnt - mean * mean, 0.f);
    float r = rsqrtf(var + EPS);
    scale = g * r;
    shift = b - mean * scale;
}

// ---------------- block reduction (blockDim.x == 256) ----------------
__device__ __forceinline__ float block_reduce_sum(float v) {
    __shared__ float s[256];
    int t = threadIdx.x;
    s[t] = v;
    __syncthreads();
    #pragma unroll
    for (int st = 128; st > 0; st >>= 1) {
        if (t < st) s[t] += s[t + st];
        __syncthreads();
    }
    float r = s[0];
    __syncthreads();
    return r;
}

// ---------------- ternarize body (device fn, uniform per block) ----------------
__device__ __forceinline__ void ternarize_body(const float* __restrict__ w,
                                               short* __restrict__ wt,
                                               float* __restrict__ alpha, int K, int f) {
    const float* wf = w + (size_t)f * K;
    short* wtf = wt + (size_t)f * K;

    float s = 0.f;
    for (int i = threadIdx.x; i < K; i += 256) s += fabsf(wf[i]);
    float total = block_reduce_sum(s);
    float delta = 0.7f * total / (float)K;

    float sm = 0.f, cm = 0.f;
    for (int i = threadIdx.x; i < K; i += 256) {
        float a = fabsf(wf[i]);
        if (a > delta) { sm += a; cm += 1.f; }
    }
    sm = block_reduce_sum(sm);
    cm = block_reduce_sum(cm);
    if (threadIdx.x == 0) alpha[f] = sm / (cm + 1e-8f);

    for (int i = threadIdx.x; i < K; i += 256) {
        float v = wf[i];
        float a = fabsf(v);
        wtf[i] = (a > delta) ? ((v > 0.f) ? (short)0x3F80 : (short)0xBF80) : (short)0;
    }
}

// ---------------- merged prep kernel: weights (ternarize+cast) PARALLEL WITH
// stats_transpose (x -> B1t + bn1 stats). Block-range dispatch (validated r11/r12).
__global__ __launch_bounds__(256) void prep_kernel(
    const float* __restrict__ w1, const float* __restrict__ w2,
    const float* __restrict__ w3, const float* __restrict__ ds_w,
    short* __restrict__ w1t, short* __restrict__ w2t, short* __restrict__ w3t,
    short* __restrict__ dswb,
    float* __restrict__ alpha1, float* __restrict__ alpha2, float* __restrict__ alpha3,
    const float* __restrict__ x, short* __restrict__ B1t,
    float* __restrict__ sum1, float* __restrict__ sq1) {
    int b = blockIdx.x;
    if (b < 256)        ternarize_body(w1, w1t, alpha1, 512, b);
    else if (b < 512)   ternarize_body(w2, w2t, alpha2, 2304, b - 256);
    else if (b < 1536)  ternarize_body(w3, w3t, alpha3, 256, b - 512);
    else if (b < 3584) {
        int i = (b - 1536) * 256 + threadIdx.x;
        if (i < 1024 * 512) dswb[i] = f2bs(ds_w[i]);
    } else {
        // ---- stats_transpose body (verbatim r11, C=512 SP=784), flattened grid ----
        const int C = 512, SP = 784;
        __shared__ short tile[64][66];
        __shared__ float rs[4][64], rq[4][64];
        int bb = b - 3584;
        int n = bb / 104;             // grid.z = 64
        int ci0 = ((bb / 13) % 8) * 64;
        int p0 = (bb % 13) * 64;
        int t = threadIdx.x;
        int tx = t & 63;
        int ty4 = t >> 6;  // 0..3

        {
            int p4 = t & 15;
            int cib = t >> 4;
            int p = p0 + p4 * 4;
            bool pok = (p + 3) < SP;
            #pragma unroll
            for (int it = 0; it < 4; it++) {
                int ci = cib + it * 16;
                float4 q;
                if (pok) q = *(const float4*)(x + ((size_t)n * C + ci0 + ci) * SP + p);
                else     q = make_float4(0.f, 0.f, 0.f, 0.f);
                tile[p4 * 4 + 0][ci] = f2bs(q.x);
                tile[p4 * 4 + 1][ci] = f2bs(q.y);
                tile[p4 * 4 + 2][ci] = f2bs(q.z);
                tile[p4 * 4 + 3][ci] = f2bs(q.w);
            }
        }
        __syncthreads();

        {
            int seg = t & 7;
            #pragma unroll
            for (int it = 0; it < 2; it++) {
                int pl = (t >> 3) + it * 32;
                int pw = p0 + pl;
                if (pw < SP) {
                    short v[8];
                    #pragma unroll
                    for (int u = 0; u < 8; u++) v[u] = tile[pl][seg * 8 + u];
                    *(int4*)(B1t + ((size_t)n * SP + pw) * C + ci0 + seg * 8) = *(int4*)v;
                }
            }
        }

        float s = 0.f, s2 = 0.f;
        #pragma unroll
        for (int r = 0; r < 16; r++) {
            int pl = ty4 + r * 4;
            int pw = p0 + pl;
            if (pw < SP) {
                float v = bs2f(tile[pl][tx]);
                s += v; s2 += v * v;
            }
        }
        rs[ty4][tx] = s; rq[ty4][tx] = s2;
        __syncthreads();
        if (ty4 == 0) {
            float ts = rs[0][tx] + rs[1][tx] + rs[2][tx] + rs[3][tx];
            float tq = rq[0][tx] + rq[1][tx] + rq[2][tx] + rq[3][tx];
            atomicAdd(&sum1[ci0 + tx], ts);
            atomicAdd(&sq1[ci0 + tx], tq);
        }
    }
}

// ---------------- foldbias (+inline bn1 finalize): w1f = t*scale1, bias1 = t.shift1 ----------------
__global__ void foldbias_kernel(const short* __restrict__ wt,
                                const float* __restrict__ sum, const float* __restrict__ sq,
                                const float* __restrict__ g, const float* __restrict__ b,
                                short* __restrict__ wf, float* __restrict__ bias,
                                int K, float cnt) {
    int f = blockIdx.x;
    float s = 0.f;
    for (int k = threadIdx.x; k < K; k += blockDim.x) {
        float scale, shift;
        bn_fin(sum[k], sq[k], g[k], b[k], cnt, scale, shift);
        float tv = bs2f(wt[(size_t)f * K + k]);
        wf[(size_t)f * K + k] = f2bs(tv * scale);
        s += tv * shift;
    }
    s = block_reduce_sum(s);
    if (threadIdx.x == 0) bias[f] = s;
}

// ---------------- BN stats phase A (h2 only now) ----------------
template <typename T, int VEC>
__global__ __launch_bounds__(256) void bn_sum_kernel(
    const T* __restrict__ src, float* __restrict__ sum, float* __restrict__ sq,
    int C, int spatial, int N, int splits) {
    int c = blockIdx.x;
    int vpc = spatial / VEC;
    int total = N * vpc;
    float s = 0.f, s2 = 0.f;
    for (int v = blockIdx.y * 256 + threadIdx.x; v < total; v += splits * 256) {
        int n = v / vpc;
        int i = v - n * vpc;
        const T* p = src + ((size_t)n * C + c) * spatial + i * VEC;
        short tmp[VEC];
        if (VEC == 8) *(int4*)tmp = *(const int4*)p;
        else          *(int2*)tmp = *(const int2*)p;
        #pragma unroll
        for (int k = 0; k < VEC; k++) { float vv = bs2f(tmp[k]); s += vv; s2 += vv * vv; }
    }
    s = block_reduce_sum(s);
    s2 = block_reduce_sum(s2);
    if (threadIdx.x == 0) {
        atomicAdd(&sum[c], s);
        atomicAdd(&sq[c], s2);
    }
}

// ---------------- dual BN stats: sc (C=1024, sp=196, VEC4) + h1 (C=256, sp=784, VEC8) ----------------
template <int VEC>
__device__ __forceinline__ void bn_sum_body(const bf16* __restrict__ src, int C, int c,
                                            int spatial, int N, int splits,
                                            float* __restrict__ sum, float* __restrict__ sq) {
    int vpc = spatial / VEC;
    int total = N * vpc;
    float s = 0.f, s2 = 0.f;
    for (int v = blockIdx.y * 256 + threadIdx.x; v < total; v += splits * 256) {
        int n = v / vpc;
        int i = v - n * vpc;
        const bf16* p = src + ((size_t)n * C + c) * spatial + i * VEC;
        short tmp[VEC];
        if (VEC == 8) *(int4*)tmp = *(const int4*)p;
        else          *(int2*)tmp = *(const int2*)p;
        #pragma unroll
        for (int k = 0; k < VEC; k++) { float vv = bs2f(tmp[k]); s += vv; s2 += vv * vv; }
    }
    s = block_reduce_sum(s);
    s2 = block_reduce_sum(s2);
    if (threadIdx.x == 0) {
        atomicAdd(&sum[c], s);
        atomicAdd(&sq[c], s2);
    }
}

__global__ __launch_bounds__(256) void bn_sum_dual_kernel(
    const bf16* __restrict__ scv, const bf16* __restrict__ h1,
    float* __restrict__ sumd, float* __restrict__ sqd,
    float* __restrict__ sum2, float* __restrict__ sq2) {
    int cb = blockIdx.x;
    if (cb < 1024) bn_sum_body<4>(scv, 1024, cb, 196, 64, 8, sumd, sqd);
    else           bn_sum_body<8>(h1, 256, cb - 1024, 784, 64, 8, sum2, sq2);
}

// ---------------- affine transpose (bf16, VMEM-wide, +inline bn3 finalize): h2 -> B3t ----------------
__global__ __launch_bounds__(256) void affine_transpose_bf16_kernel(
    const bf16* __restrict__ in,
    const float* __restrict__ sum, const float* __restrict__ sq,
    const float* __restrict__ g, const float* __restrict__ b, float cnt,
    short* __restrict__ Bt, int C, int SP) {
    __shared__ short tile[64][66];
    int n = blockIdx.z;
    int ci0 = blockIdx.y * 64;
    int p0 = blockIdx.x * 64;
    int t = threadIdx.x;

    {
        int p4 = t & 15;
        int cib = t >> 4;
        int p = p0 + p4 * 4;
        bool pok = (p + 3) < SP;          // SP%4==0
        #pragma unroll
        for (int it = 0; it < 4; it++) {
            int ci = cib + it * 16;
            short v[4] = {0, 0, 0, 0};
            if (pok) *(int2*)v = *(const int2*)(in + ((size_t)n * C + ci0 + ci) * SP + p);
            float sc, sh;
            bn_fin(sum[ci0 + ci], sq[ci0 + ci], g[ci0 + ci], b[ci0 + ci], cnt, sc, sh);
            #pragma unroll
            for (int j = 0; j < 4; j++)
                tile[p4 * 4 + j][ci] = f2bs(bs2f(v[j]) * sc + sh);
        }
    }
    __syncthreads();

    {
        int seg = t & 7;
        #pragma unroll
        for (int it = 0; it < 2; it++) {
            int pl = (t >> 3) + it * 32;
            int pw = p0 + pl;
            if (pw < SP) {
                short v[8];
                #pragma unroll
                for (int u = 0; u < 8; u++) v[u] = tile[pl][seg * 8 + u];
                *(int4*)(Bt + ((size_t)n * SP + pw) * C + ci0 + seg * 8) = *(int4*)v;
            }
        }
    }
}

// ---------------- LDS-tiled im2col (+inline bn2 finalize) for conv2 (3x3 s2 p1) ----------------
__global__ __launch_bounds__(256) void im2col_tiled_kernel(
    const bf16* __restrict__ h1,
    const float* __restrict__ sum, const float* __restrict__ sq,
    const float* __restrict__ g, const float* __restrict__ b, float cnt,
    short* __restrict__ B2t) {
    __shared__ short tile[16][784];   // 25 KB
    int cb = blockIdx.x;              // 0..15 (16-channel slab)
    int n  = blockIdx.y;              // 0..63
    int ci0 = cb * 16;
    int t = threadIdx.x;

    for (int v = t; v < 16 * 98; v += 256) {
        int ci = v / 98;
        int i8 = (v - ci * 98) * 8;
        short tmp[8];
        *(int4*)tmp = *(const int4*)(h1 + ((size_t)n * 256 + ci0 + ci) * 784 + i8);
        float sc, sh;
        bn_fin(sum[ci0 + ci], sq[ci0 + ci], g[ci0 + ci], b[ci0 + ci], cnt, sc, sh);
        short ov[8];
        #pragma unroll
        for (int k = 0; k < 8; k++) ov[k] = f2bs(bs2f(tmp[k]) * sc + sh);
        *(int4*)&tile[ci][i8] = *(int4*)ov;
    }
    __syncthreads();

    for (int w = t; w < 196 * 18; w += 256) {
        int p = w / 18, seg = w - p * 18;
        int oh = p / 14, ow = p - oh * 14;
        int kbase = seg * 8;
        short vals[8];
        #pragma unroll
        for (int u = 0; u < 8; u++) {
            int kk = kbase + u;
            int ci_l = kk / 9;
            int rr = kk - ci_l * 9;
            int kh = rr / 3, kw = rr - kh * 3;
            int ih = 2 * oh - 1 + kh;
            int iw = 2 * ow - 1 + kw;
            vals[u] = ((unsigned)ih < 28u && (unsigned)iw < 28u)
                          ? tile[ci_l][ih * 28 + iw] : (short)0;
        }
        *(int4*)(B2t + ((size_t)(n * 196 + p)) * 2304 + ci0 * 9 + kbase) = *(int4*)vals;
    }
}

// ---------------- merged GEMM1 || GEMM4 (independent given B1t) ----------------
// r13 fix: UNION the two branches' LDS (one 16KB array, aliased) — r12's separate
// static arrays summed to 24KB/block, capping residency at 6 blocks/CU (counter:
// LDS_Block_Size=24576, Occupancy 19.5%). Also INTERLEAVE branches (every 5th
// block is GEMM1; 3920/5=784 exactly) so heavy/light blocks co-reside per CU.
// K-loop bodies verbatim (r7 128^2 / r9 64^2).
__global__ __launch_bounds__(256) void gemm14_kernel(
    const short* __restrict__ w1f, const short* __restrict__ dswb,
    const short* __restrict__ B1t,
    const float* __restrict__ alpha1, const float* __restrict__ bias1,
    bf16* __restrict__ h1, bf16* __restrict__ sc) {
    __shared__ short lds[8192];   // 16 KB union: G1 {As=lds, Bs=lds+4096}; G4 {As=lds, Bs=lds+2048}
    int blk = blockIdx.x;
    int t = threadIdx.x;
    int w = t >> 6, l = t & 63;
    int r0 = t >> 2;
    int kg = (t & 3) * 8;
    int wbase = w * 512;
    int lm = (l >> 4);
    int lc = l & 15;

    if (blk % 5 == 0) {
        // ======== GEMM1: 128x128, M=256, K=512, SP=784 (idx = blk/5, 784 blocks) ========
        short* As = lds;
        short* Bs = lds + 4096;
        const int SP = 784, M = 256, K = 512;
        int idx = blk / 5;
        int c0 = (idx % 392) * 128;
        int m0 = (idx / 392) * 128;
        int wm = (w >> 1) * 64, wn = (w & 1) * 64;
        size_t rowB0 = c0 + r0;
        size_t rowB1 = c0 + r0 + 64;

        float4v acc[4][4];
        #pragma unroll
        for (int i = 0; i < 4; i++)
            #pragma unroll
            for (int j = 0; j < 4; j++) acc[i][j] = (float4v)0.f;

        for (int k0 = 0; k0 < K; k0 += 32) {
            gload_lds16(w1f + (size_t)(m0 + r0) * K + k0 + kg,      &As[wbase]);
            gload_lds16(w1f + (size_t)(m0 + r0 + 64) * K + k0 + kg, &As[2048 + wbase]);
            gload_lds16(B1t + rowB0 * K + k0 + kg,                  &Bs[wbase]);
            gload_lds16(B1t + rowB1 * K + k0 + kg,                  &Bs[2048 + wbase]);
            __syncthreads();

            short8 af[4], bfr[4];
            #pragma unroll
            for (int i = 0; i < 4; i++)
                af[i] = *(const short8*)&As[(wm + i * 16 + lc) * 32 + lm * 8];
            #pragma unroll
            for (int j = 0; j < 4; j++)
                bfr[j] = *(const short8*)&Bs[(wn + j * 16 + lc) * 32 + lm * 8];
            #pragma unroll
            for (int i = 0; i < 4; i++)
                #pragma unroll
                for (int j = 0; j < 4; j++)
                    acc[i][j] = __builtin_amdgcn_mfma_f32_16x16x32_bf16(af[i], bfr[j], acc[i][j], 0, 0, 0);
            __syncthreads();
        }

        #pragma unroll
        for (int i = 0; i < 4; i++) {
            #pragma unroll
            for (int r = 0; r < 4; r++) {
                int m = m0 + wm + i * 16 + lm * 4 + r;
                float a = alpha1[m];
                float bia = bias1[m];
                #pragma unroll
                for (int j = 0; j < 4; j++) {
                    int c = c0 + wn + j * 16 + lc;
                    int n = c / SP;
                    int p = c - n * SP;
                    h1[((size_t)n * M + m) * SP + p] = __float2bfloat16((acc[i][j][r] + bia) * a);
                }
            }
        }
    } else {
        // ======== GEMM4: 64x64 + stride-2 remap, M=1024, K=512 (3136 blocks) ========
        short* As4 = lds;
        short* Bs4 = lds + 2048;
        const int SP = 196, M = 1024, K = 512;
        int bb = blk - blk / 5 - 1;     // 0..3135
        int c0 = (bb % 196) * 64;
        int m0 = (bb / 196) * 64;
        int wm = (w >> 1) * 32, wn = (w & 1) * 32;

        int c = c0 + r0;
        int nn = c / 196, pp = c - nn * 196;
        int oh = pp / 14, ow = pp - oh * 14;
        size_t rowB = (size_t)nn * 784 + oh * 56 + ow * 2;

        float4v acc[2][2];
        #pragma unroll
        for (int i = 0; i < 2; i++)
            #pragma unroll
            for (int j = 0; j < 2; j++) acc[i][j] = (float4v)0.f;

        for (int k0 = 0; k0 < K; k0 += 32) {
            gload_lds16(dswb + (size_t)(m0 + r0) * K + k0 + kg, &As4[wbase]);
            gload_lds16(B1t + rowB * K + k0 + kg,               &Bs4[wbase]);
            __syncthreads();

            short8 af[2], bfr[2];
            #pragma unroll
            for (int i = 0; i < 2; i++)
                af[i] = *(const short8*)&As4[(wm + i * 16 + lc) * 32 + lm * 8];
            #pragma unroll
            for (int j = 0; j < 2; j++)
                bfr[j] = *(const short8*)&Bs4[(wn + j * 16 + lc) * 32 + lm * 8];
            #pragma unroll
            for (int i = 0; i < 2; i++)
                #pragma unroll
                for (int j = 0; j < 2; j++)
                    acc[i][j] = __builtin_amdgcn_mfma_f32_16x16x32_bf16(af[i], bfr[j], acc[i][j], 0, 0, 0);
            __syncthreads();
        }

        #pragma unroll
        for (int i = 0; i < 2; i++) {
            #pragma unroll
            for (int r = 0; r < 4; r++) {
                int m = m0 + wm + i * 16 + lm * 4 + r;
                #pragma unroll
                for (int j = 0; j < 2; j++) {
                    int cc = c0 + wn + j * 16 + lc;
                    int n = cc / SP;
                    int p = cc - n * SP;
                    sc[((size_t)n * M + m) * SP + p] = __float2bfloat16(acc[i][j][r]);
                }
            }
        }
    }
}

// ---------------- MFMA GEMM (128x128 tile, BK=32, 4 waves, 4x4 16x16x32) ----------------
// K-loop VERBATIM from round-7 (verified). Used for GEMM3 only. FUSE epilogue
// computes ds-BN scale/shift inline from raw stats.
template <int SP, typename TOut, bool HAS_ALPHA, bool FUSE, bool HAS_BIAS, bool BREMAP>
__global__ __launch_bounds__(256) void gemm_kernel(
    const short* __restrict__ A, const short* __restrict__ Bt,
    const float* __restrict__ alpha, TOut* __restrict__ out,
    int M, int K,
    const bf16* __restrict__ scv,
    const float* __restrict__ fsum, const float* __restrict__ fsq,
    const float* __restrict__ fg, const float* __restrict__ fb, float fcnt,
    const float* __restrict__ bias) {
    __shared__ short As[128 * 32];
    __shared__ short Bs[128 * 32];
    int t = threadIdx.x;
    int c0 = blockIdx.x * 128;
    int m0 = blockIdx.y * 128;
    int w = t >> 6, l = t & 63;
    int wm = (w >> 1) * 64, wn = (w & 1) * 64;

    int r0 = t >> 2;
    int kg = (t & 3) * 8;
    int wbase = w * 512;

    size_t rowB0, rowB1;
    if (BREMAP) {
        int c = c0 + r0;
        int nn = c / 196, pp = c - nn * 196;
        int oh = pp / 14, ow = pp - oh * 14;
        rowB0 = (size_t)nn * 784 + oh * 56 + ow * 2;
        c += 64;
        nn = c / 196; pp = c - nn * 196;
        oh = pp / 14; ow = pp - oh * 14;
        rowB1 = (size_t)nn * 784 + oh * 56 + ow * 2;
    } else {
        rowB0 = c0 + r0;
        rowB1 = c0 + r0 + 64;
    }

    float4v acc[4][4];
    #pragma unroll
    for (int i = 0; i < 4; i++)
        #pragma unroll
        for (int j = 0; j < 4; j++) acc[i][j] = (float4v)0.f;

    int lm = (l >> 4);
    int lc = l & 15;

    for (int k0 = 0; k0 < K; k0 += 32) {
        gload_lds16(A + (size_t)(m0 + r0) * K + k0 + kg,      &As[wbase]);
        gload_lds16(A + (size_t)(m0 + r0 + 64) * K + k0 + kg, &As[2048 + wbase]);
        gload_lds16(Bt + rowB0 * K + k0 + kg,                 &Bs[wbase]);
        gload_lds16(Bt + rowB1 * K + k0 + kg,                 &Bs[2048 + wbase]);
        __syncthreads();

        short8 af[4], bfr[4];
        #pragma unroll
        for (int i = 0; i < 4; i++)
            af[i] = *(const short8*)&As[(wm + i * 16 + lc) * 32 + lm * 8];
        #pragma unroll
        for (int j = 0; j < 4; j++)
            bfr[j] = *(const short8*)&Bs[(wn + j * 16 + lc) * 32 + lm * 8];
        #pragma unroll
        for (int i = 0; i < 4; i++)
            #pragma unroll
            for (int j = 0; j < 4; j++)
                acc[i][j] = __builtin_amdgcn_mfma_f32_16x16x32_bf16(af[i], bfr[j], acc[i][j], 0, 0, 0);
        __syncthreads();
    }

    #pragma unroll
    for (int i = 0; i < 4; i++) {
        #pragma unroll
        for (int r = 0; r < 4; r++) {
            int m = m0 + wm + i * 16 + lm * 4 + r;
            float a = HAS_ALPHA ? alpha[m] : 1.f;
            float bia = HAS_BIAS ? bias[m] : 0.f;
            float fsc = 0.f, fsh = 0.f;
            if (FUSE) bn_fin(fsum[m], fsq[m], fg[m], fb[m], fcnt, fsc, fsh);
            #pragma unroll
            for (int j = 0; j < 4; j++) {
                int c = c0 + wn + j * 16 + lc;
                int n = c / SP;
                int p = c - n * SP;
                size_t idx = ((size_t)n * M + m) * SP + p;
                float v = acc[i][j][r];
                if (HAS_BIAS) v += bia;
                if (HAS_ALPHA) v *= a;
                if (FUSE) v += toF(scv[idx]) * fsc + fsh;
                stF(&out[idx], v);
            }
        }
    }
}

// ---------------- GEMM2-dedicated kernel: 64x64 tile (784 blocks) ----------------
// Verbatim round-7 body.
__global__ __launch_bounds__(256) void gemm2_kernel(
    const short* __restrict__ A, const short* __restrict__ Bt,
    const float* __restrict__ alpha, bf16* __restrict__ out,
    int M, int K) {
    constexpr int SP = 196;
    __shared__ short As[64 * 32];
    __shared__ short Bs[64 * 32];
    int t = threadIdx.x;
    int c0 = blockIdx.x * 64;
    int m0 = blockIdx.y * 64;
    int w = t >> 6, l = t & 63;
    int wm = (w >> 1) * 32, wn = (w & 1) * 32;

    int r0 = t >> 2;          // 0..63
    int kg = (t & 3) * 8;     // 0,8,16,24
    int wbase = w * 512;

    float4v acc[2][2];
    #pragma unroll
    for (int i = 0; i < 2; i++)
        #pragma unroll
        for (int j = 0; j < 2; j++) acc[i][j] = (float4v)0.f;

    int lm = (l >> 4);
    int lc = l & 15;

    for (int k0 = 0; k0 < K; k0 += 32) {
        gload_lds16(A + (size_t)(m0 + r0) * K + k0 + kg,  &As[wbase]);
        gload_lds16(Bt + (size_t)(c0 + r0) * K + k0 + kg, &Bs[wbase]);
        __syncthreads();

        short8 af[2], bfr[2];
        #pragma unroll
        for (int i = 0; i < 2; i++)
            af[i] = *(const short8*)&As[(wm + i * 16 + lc) * 32 + lm * 8];
        #pragma unroll
        for (int j = 0; j < 2; j++)
            bfr[j] = *(const short8*)&Bs[(wn + j * 16 + lc) * 32 + lm * 8];
        #pragma unroll
        for (int i = 0; i < 2; i++)
            #pragma unroll
            for (int j = 0; j < 2; j++)
                acc[i][j] = __builtin_amdgcn_mfma_f32_16x16x32_bf16(af[i], bfr[j], acc[i][j], 0, 0, 0);
        __syncthreads();
    }

    #pragma unroll
    for (int i = 0; i < 2; i++) {
        #pragma unroll
        for (int r = 0; r < 4; r++) {
            int m = m0 + wm + i * 16 + lm * 4 + r;
            float a = alpha[m];
            #pragma unroll
            for (int j = 0; j < 2; j++) {
                int c = c0 + wn + j * 16 + lc;
                int n = c / SP;
                int p = c - n * SP;
                out[((size_t)n * M + m) * SP + p] = __float2bfloat16(acc[i][j][r] * a);
            }
        }
    }
}

extern "C" void kernel_launch(void* const* d_in, const int* in_sizes, int n_in,
                              void* d_out, int out_size, void* d_ws, size_t ws_size,
                              hipStream_t stream) {
    const float* x      = (const float*)d_in[0];   // (64,512,28,28)
    const float* bn1_g  = (const float*)d_in[1];
    const float* bn1_b  = (const float*)d_in[2];
    const float* w1     = (const float*)d_in[3];   // (256,512,1,1)
    const float* bn2_g  = (const float*)d_in[4];
    const float* bn2_b  = (const float*)d_in[5];
    const float* w2     = (const float*)d_in[6];   // (256,256,3,3)
    const float* bn3_g  = (const float*)d_in[7];
    const float* bn3_b  = (const float*)d_in[8];
    const float* w3     = (const float*)d_in[9];   // (1024,256,1,1)
    const float* ds_w   = (const float*)d_in[10];  // (1024,512,1,1) NOT ternarized
    const float* dbn_g  = (const float*)d_in[11];
    const float* dbn_b  = (const float*)d_in[12];
    float* out = (float*)d_out;

    const int N = 64, C1 = 512, C2 = 256, C3 = 1024;
    const int SP1 = 784, SP2 = 196;
    const int NT1 = N * SP1;   // 50176
    const int NT2 = N * SP2;   // 12544

    // ---- workspace layout ----
    char* wsb = (char*)d_ws;
    size_t off = 0;
    auto alloc = [&](size_t bytes) { char* p = wsb + off; off += (bytes + 255) & ~(size_t)255; return p; };

    char* pool = alloc((size_t)NT2 * 2304 * 2);   // 57.8 MB: B1t (51.4) / B2t (57.8) / B3t (6.4) time-share
    short* B1t = (short*)pool;                    // raw bf16(x)^T; live until GEMM1||GEMM4
    short* B2t = (short*)pool;                    // created by im2col AFTER gemm14
    short* B3t = (short*)pool;                    // created after B2t is dead
    bf16*  sc  = (bf16*)alloc((size_t)N * C3 * SP2 * 2);  // 25.7 MB, own region

    bf16* h1 = (bf16*)alloc((size_t)N * C2 * SP1 * 2);
    bf16* h2 = (bf16*)alloc((size_t)N * C2 * SP2 * 2);
    short* w1t  = (short*)alloc((size_t)C2 * C1 * 2);
    short* w1f  = (short*)alloc((size_t)C2 * C1 * 2);   // scale-folded w1
    short* w2t  = (short*)alloc((size_t)C2 * C2 * 9 * 2);
    short* w3t  = (short*)alloc((size_t)C3 * C2 * 2);
    short* dswb = (short*)alloc((size_t)C3 * C1 * 2);
    float* alpha1 = (float*)alloc(C2 * 4);
    float* alpha2 = (float*)alloc(C2 * 4);
    float* alpha3 = (float*)alloc(C3 * 4);
    float* bias1  = (float*)alloc(C2 * 4);
    float* acc_base = (float*)alloc((size_t)(C1 + C2 + C2 + C3) * 2 * 4);
    float* sum1 = acc_base;            float* sq1 = sum1 + C1;
    float* sum2 = sq1 + C1;            float* sq2 = sum2 + C2;
    float* sum3 = sq2 + C2;            float* sq3 = sum3 + C2;
    float* sumd = sq3 + C2;            float* sqd = sumd + C3;
    (void)ws_size; (void)in_sizes; (void)n_in; (void)out_size;

    // 1) zero BN accumulators
    hipMemsetAsync(acc_base, 0, (size_t)(C1 + C2 + C2 + C3) * 2 * 4, stream);

    // 2) merged prep: weights (ternarize+cast) || stats_transpose (x -> B1t + bn1 stats)
    prep_kernel<<<10240, 256, 0, stream>>>(w1, w2, w3, ds_w, w1t, w2t, w3t, dswb,
                                           alpha1, alpha2, alpha3, x, B1t, sum1, sq1);

    // 3) foldbias (+inline bn1 finalize): w1f, bias1
    foldbias_kernel<<<C2, 256, 0, stream>>>(w1t, sum1, sq1, bn1_g, bn1_b,
                                            w1f, bias1, C1, (float)(N * SP1));

    // 4) merged GEMM1 || GEMM4 (LDS union + interleave): h1 and sc
    gemm14_kernel<<<3920, 256, 0, stream>>>(w1f, dswb, B1t, alpha1, bias1, h1, sc);

    // 5) dual BN stats: sc -> sumd/sqd, h1 -> sum2/sq2
    bn_sum_dual_kernel<<<dim3(C3 + C2, 8), 256, 0, stream>>>(
        sc, h1, sumd, sqd, sum2, sq2);

    // 6) im2col (+inline bn2 finalize) -> B2t (overwrites pool; B1t dead)
    im2col_tiled_kernel<<<dim3(16, 64), 256, 0, stream>>>(
        h1, sum2, sq2, bn2_g, bn2_b, (float)(N * SP1), B2t);

    // 7) GEMM2 (64x64): h2 = alpha2 * (w2t . B2t^T)   M=256 K=2304
    gemm2_kernel<<<dim3(NT2 / 64, C2 / 64), 256, 0, stream>>>(
        w2t, B2t, alpha2, h2, C2, C2 * 9);

    // 8) bn3 stats on h2
    bn_sum_kernel<bf16, 4><<<dim3(C2, 4), 256, 0, stream>>>(h2, sum3, sq3, C2, SP2, N, 4);

    // 9) B3t = bn3(h2)^T (+inline bn3 finalize)
    {
        dim3 grid((SP2 + 63) / 64, C2 / 64, N);
        affine_transpose_bf16_kernel<<<grid, 256, 0, stream>>>(
            h2, sum3, sq3, bn3_g, bn3_b, (float)(N * SP2), B3t, C2, SP2);
    }

    // 10) GEMM3 with fused residual (+inline ds-bn finalize):
    //     out = alpha3*(w3t . B3t^T) + sc*scaled + shiftd
    gemm_kernel<196, float, true, true, false, false>
        <<<dim3(NT2 / 128, C3 / 128), 256, 0, stream>>>(
        w3t, B3t, alpha3, out, C3, C2,
        sc, sumd, sqd, dbn_g, dbn_b, (float)(N * SP2), nullptr);
}

// Round 15
// 397.071 us; speedup vs baseline: 1.0275x; 1.0275x over previous
//
#include <hip/hip_runtime.h>
#include <hip/hip_bf16.h>
#include <math.h>

#define EPS 1e-5f

typedef __hip_bfloat16 bf16;
typedef short short8 __attribute__((ext_vector_type(8)));
typedef float float4v __attribute__((ext_vector_type(4)));

__device__ __forceinline__ float toF(float v) { return v; }
__device__ __forceinline__ float toF(bf16 v) { return __bfloat162float(v); }
__device__ __forceinline__ void stF(float* p, float v) { *p = v; }
__device__ __forceinline__ void stF(bf16* p, float v) { *p = __float2bfloat16(v); }
__device__ __forceinline__ short f2bs(float v) {
    bf16 b = __float2bfloat16(v);
    return *reinterpret_cast<short*>(&b);
}
__device__ __forceinline__ float bs2f(short s) {
    unsigned u = ((unsigned)(unsigned short)s) << 16;
    return __uint_as_float(u);
}

// direct global->LDS DMA, 16B per lane. LDS dest: wave-uniform base + lane*16.
__device__ __forceinline__ void gload_lds16(const short* g, short* l) {
    __builtin_amdgcn_global_load_lds(
        (const __attribute__((address_space(1))) unsigned int*)g,
        (__attribute__((address_space(3))) unsigned int*)l, 16, 0, 0);
}

// BN finalize formula (identical to the removed bn_finalize_kernel)
__device__ __forceinline__ void bn_fin(float sum, float sq, float g, float b, float cnt,
                                       float& scale, float& shift) {
    float mean = sum / cnt;
    float var = fmaxf(sq / cnt - mean * mean, 0.f);
    float r = rsqrtf(var + EPS);
    scale = g * r;
    shift = b - mean * scale;
}

// ---------------- block reduction (blockDim.x == 256) ----------------
__device__ __forceinline__ float block_reduce_sum(float v) {
    __shared__ float s[256];
    int t = threadIdx.x;
    s[t] = v;
    __syncthreads();
    #pragma unroll
    for (int st = 128; st > 0; st >>= 1) {
        if (t < st) s[t] += s[t + st];
        __syncthreads();
    }
    float r = s[0];
    __syncthreads();
    return r;
}

// ---------------- ternarize body (device fn, uniform per block) ----------------
__device__ __forceinline__ void ternarize_body(const float* __restrict__ w,
                                               short* __restrict__ wt,
                                               float* __restrict__ alpha, int K, int f) {
    const float* wf = w + (size_t)f * K;
    short* wtf = wt + (size_t)f * K;

    float s = 0.f;
    for (int i = threadIdx.x; i < K; i += 256) s += fabsf(wf[i]);
    float total = block_reduce_sum(s);
    float delta = 0.7f * total / (float)K;

    float sm = 0.f, cm = 0.f;
    for (int i = threadIdx.x; i < K; i += 256) {
        float a = fabsf(wf[i]);
        if (a > delta) { sm += a; cm += 1.f; }
    }
    sm = block_reduce_sum(sm);
    cm = block_reduce_sum(cm);
    if (threadIdx.x == 0) alpha[f] = sm / (cm + 1e-8f);

    for (int i = threadIdx.x; i < K; i += 256) {
        float v = wf[i];
        float a = fabsf(v);
        wtf[i] = (a > delta) ? ((v > 0.f) ? (short)0x3F80 : (short)0xBF80) : (short)0;
    }
}

// ---------------- merged prep kernel: weights (ternarize+cast) PARALLEL WITH
// stats_transpose (x -> B1t + bn1 stats). Block-range dispatch (validated r11/r12).
__global__ __launch_bounds__(256) void prep_kernel(
    const float* __restrict__ w1, const float* __restrict__ w2,
    const float* __restrict__ w3, const float* __restrict__ ds_w,
    short* __restrict__ w1t, short* __restrict__ w2t, short* __restrict__ w3t,
    short* __restrict__ dswb,
    float* __restrict__ alpha1, float* __restrict__ alpha2, float* __restrict__ alpha3,
    const float* __restrict__ x, short* __restrict__ B1t,
    float* __restrict__ sum1, float* __restrict__ sq1) {
    int b = blockIdx.x;
    if (b < 256)        ternarize_body(w1, w1t, alpha1, 512, b);
    else if (b < 512)   ternarize_body(w2, w2t, alpha2, 2304, b - 256);
    else if (b < 1536)  ternarize_body(w3, w3t, alpha3, 256, b - 512);
    else if (b < 3584) {
        int i = (b - 1536) * 256 + threadIdx.x;
        if (i < 1024 * 512) dswb[i] = f2bs(ds_w[i]);
    } else {
        // ---- stats_transpose body (verbatim r11, C=512 SP=784), flattened grid ----
        const int C = 512, SP = 784;
        __shared__ short tile[64][66];
        __shared__ float rs[4][64], rq[4][64];
        int bb = b - 3584;
        int n = bb / 104;             // grid.z = 64
        int ci0 = ((bb / 13) % 8) * 64;
        int p0 = (bb % 13) * 64;
        int t = threadIdx.x;
        int tx = t & 63;
        int ty4 = t >> 6;  // 0..3

        {
            int p4 = t & 15;
            int cib = t >> 4;
            int p = p0 + p4 * 4;
            bool pok = (p + 3) < SP;
            #pragma unroll
            for (int it = 0; it < 4; it++) {
                int ci = cib + it * 16;
                float4 q;
                if (pok) q = *(const float4*)(x + ((size_t)n * C + ci0 + ci) * SP + p);
                else     q = make_float4(0.f, 0.f, 0.f, 0.f);
                tile[p4 * 4 + 0][ci] = f2bs(q.x);
                tile[p4 * 4 + 1][ci] = f2bs(q.y);
                tile[p4 * 4 + 2][ci] = f2bs(q.z);
                tile[p4 * 4 + 3][ci] = f2bs(q.w);
            }
        }
        __syncthreads();

        {
            int seg = t & 7;
            #pragma unroll
            for (int it = 0; it < 2; it++) {
                int pl = (t >> 3) + it * 32;
                int pw = p0 + pl;
                if (pw < SP) {
                    short v[8];
                    #pragma unroll
                    for (int u = 0; u < 8; u++) v[u] = tile[pl][seg * 8 + u];
                    *(int4*)(B1t + ((size_t)n * SP + pw) * C + ci0 + seg * 8) = *(int4*)v;
                }
            }
        }

        float s = 0.f, s2 = 0.f;
        #pragma unroll
        for (int r = 0; r < 16; r++) {
            int pl = ty4 + r * 4;
            int pw = p0 + pl;
            if (pw < SP) {
                float v = bs2f(tile[pl][tx]);
                s += v; s2 += v * v;
            }
        }
        rs[ty4][tx] = s; rq[ty4][tx] = s2;
        __syncthreads();
        if (ty4 == 0) {
            float ts = rs[0][tx] + rs[1][tx] + rs[2][tx] + rs[3][tx];
            float tq = rq[0][tx] + rq[1][tx] + rq[2][tx] + rq[3][tx];
            atomicAdd(&sum1[ci0 + tx], ts);
            atomicAdd(&sq1[ci0 + tx], tq);
        }
    }
}

// ---------------- foldbias (+inline bn1 finalize): w1f = t*scale1, bias1 = t.shift1 ----------------
__global__ void foldbias_kernel(const short* __restrict__ wt,
                                const float* __restrict__ sum, const float* __restrict__ sq,
                                const float* __restrict__ g, const float* __restrict__ b,
                                short* __restrict__ wf, float* __restrict__ bias,
                                int K, float cnt) {
    int f = blockIdx.x;
    float s = 0.f;
    for (int k = threadIdx.x; k < K; k += blockDim.x) {
        float scale, shift;
        bn_fin(sum[k], sq[k], g[k], b[k], cnt, scale, shift);
        float tv = bs2f(wt[(size_t)f * K + k]);
        wf[(size_t)f * K + k] = f2bs(tv * scale);
        s += tv * shift;
    }
    s = block_reduce_sum(s);
    if (threadIdx.x == 0) bias[f] = s;
}

// ---------------- BN stats phase A (h2 only now) ----------------
template <typename T, int VEC>
__global__ __launch_bounds__(256) void bn_sum_kernel(
    const T* __restrict__ src, float* __restrict__ sum, float* __restrict__ sq,
    int C, int spatial, int N, int splits) {
    int c = blockIdx.x;
    int vpc = spatial / VEC;
    int total = N * vpc;
    float s = 0.f, s2 = 0.f;
    for (int v = blockIdx.y * 256 + threadIdx.x; v < total; v += splits * 256) {
        int n = v / vpc;
        int i = v - n * vpc;
        const T* p = src + ((size_t)n * C + c) * spatial + i * VEC;
        short tmp[VEC];
        if (VEC == 8) *(int4*)tmp = *(const int4*)p;
        else          *(int2*)tmp = *(const int2*)p;
        #pragma unroll
        for (int k = 0; k < VEC; k++) { float vv = bs2f(tmp[k]); s += vv; s2 += vv * vv; }
    }
    s = block_reduce_sum(s);
    s2 = block_reduce_sum(s2);
    if (threadIdx.x == 0) {
        atomicAdd(&sum[c], s);
        atomicAdd(&sq[c], s2);
    }
}

// ---------------- dual BN stats: sc (C=1024, sp=196, VEC4) + h1 (C=256, sp=784, VEC8) ----------------
template <int VEC>
__device__ __forceinline__ void bn_sum_body(const bf16* __restrict__ src, int C, int c,
                                            int spatial, int N, int splits,
                                            float* __restrict__ sum, float* __restrict__ sq) {
    int vpc = spatial / VEC;
    int total = N * vpc;
    float s = 0.f, s2 = 0.f;
    for (int v = blockIdx.y * 256 + threadIdx.x; v < total; v += splits * 256) {
        int n = v / vpc;
        int i = v - n * vpc;
        const bf16* p = src + ((size_t)n * C + c) * spatial + i * VEC;
        short tmp[VEC];
        if (VEC == 8) *(int4*)tmp = *(const int4*)p;
        else          *(int2*)tmp = *(const int2*)p;
        #pragma unroll
        for (int k = 0; k < VEC; k++) { float vv = bs2f(tmp[k]); s += vv; s2 += vv * vv; }
    }
    s = block_reduce_sum(s);
    s2 = block_reduce_sum(s2);
    if (threadIdx.x == 0) {
        atomicAdd(&sum[c], s);
        atomicAdd(&sq[c], s2);
    }
}

__global__ __launch_bounds__(256) void bn_sum_dual_kernel(
    const bf16* __restrict__ scv, const bf16* __restrict__ h1,
    float* __restrict__ sumd, float* __restrict__ sqd,
    float* __restrict__ sum2, float* __restrict__ sq2) {
    int cb = blockIdx.x;
    if (cb < 1024) bn_sum_body<4>(scv, 1024, cb, 196, 64, 8, sumd, sqd);
    else           bn_sum_body<8>(h1, 256, cb - 1024, 784, 64, 8, sum2, sq2);
}

// ---------------- affine transpose (bf16, VMEM-wide, +inline bn3 finalize): h2 -> B3t ----------------
__global__ __launch_bounds__(256) void affine_transpose_bf16_kernel(
    const bf16* __restrict__ in,
    const float* __restrict__ sum, const float* __restrict__ sq,
    const float* __restrict__ g, const float* __restrict__ b, float cnt,
    short* __restrict__ Bt, int C, int SP) {
    __shared__ short tile[64][66];
    int n = blockIdx.z;
    int ci0 = blockIdx.y * 64;
    int p0 = blockIdx.x * 64;
    int t = threadIdx.x;

    {
        int p4 = t & 15;
        int cib = t >> 4;
        int p = p0 + p4 * 4;
        bool pok = (p + 3) < SP;          // SP%4==0
        #pragma unroll
        for (int it = 0; it < 4; it++) {
            int ci = cib + it * 16;
            short v[4] = {0, 0, 0, 0};
            if (pok) *(int2*)v = *(const int2*)(in + ((size_t)n * C + ci0 + ci) * SP + p);
            float sc, sh;
            bn_fin(sum[ci0 + ci], sq[ci0 + ci], g[ci0 + ci], b[ci0 + ci], cnt, sc, sh);
            #pragma unroll
            for (int j = 0; j < 4; j++)
                tile[p4 * 4 + j][ci] = f2bs(bs2f(v[j]) * sc + sh);
        }
    }
    __syncthreads();

    {
        int seg = t & 7;
        #pragma unroll
        for (int it = 0; it < 2; it++) {
            int pl = (t >> 3) + it * 32;
            int pw = p0 + pl;
            if (pw < SP) {
                short v[8];
                #pragma unroll
                for (int u = 0; u < 8; u++) v[u] = tile[pl][seg * 8 + u];
                *(int4*)(Bt + ((size_t)n * SP + pw) * C + ci0 + seg * 8) = *(int4*)v;
            }
        }
    }
}

// ---------------- LDS-tiled im2col (+inline bn2 finalize) for conv2 (3x3 s2 p1) ----------------
__global__ __launch_bounds__(256) void im2col_tiled_kernel(
    const bf16* __restrict__ h1,
    const float* __restrict__ sum, const float* __restrict__ sq,
    const float* __restrict__ g, const float* __restrict__ b, float cnt,
    short* __restrict__ B2t) {
    __shared__ short tile[16][784];   // 25 KB
    int cb = blockIdx.x;              // 0..15 (16-channel slab)
    int n  = blockIdx.y;              // 0..63
    int ci0 = cb * 16;
    int t = threadIdx.x;

    for (int v = t; v < 16 * 98; v += 256) {
        int ci = v / 98;
        int i8 = (v - ci * 98) * 8;
        short tmp[8];
        *(int4*)tmp = *(const int4*)(h1 + ((size_t)n * 256 + ci0 + ci) * 784 + i8);
        float sc, sh;
        bn_fin(sum[ci0 + ci], sq[ci0 + ci], g[ci0 + ci], b[ci0 + ci], cnt, sc, sh);
        short ov[8];
        #pragma unroll
        for (int k = 0; k < 8; k++) ov[k] = f2bs(bs2f(tmp[k]) * sc + sh);
        *(int4*)&tile[ci][i8] = *(int4*)ov;
    }
    __syncthreads();

    for (int w = t; w < 196 * 18; w += 256) {
        int p = w / 18, seg = w - p * 18;
        int oh = p / 14, ow = p - oh * 14;
        int kbase = seg * 8;
        short vals[8];
        #pragma unroll
        for (int u = 0; u < 8; u++) {
            int kk = kbase + u;
            int ci_l = kk / 9;
            int rr = kk - ci_l * 9;
            int kh = rr / 3, kw = rr - kh * 3;
            int ih = 2 * oh - 1 + kh;
            int iw = 2 * ow - 1 + kw;
            vals[u] = ((unsigned)ih < 28u && (unsigned)iw < 28u)
                          ? tile[ci_l][ih * 28 + iw] : (short)0;
        }
        *(int4*)(B2t + ((size_t)(n * 196 + p)) * 2304 + ci0 * 9 + kbase) = *(int4*)vals;
    }
}

// ---------------- merged GEMM1 || GEMM4 (independent given B1t) ----------------
// r14: r12-verbatim structure (contiguous branch ranges [0,784)/[784,3920),
// separate static LDS — r13's interleave cost +48MB FETCH / +10us, reverted;
// LDS union was a no-op since occupancy is VGPR-bound at 5 blocks/CU).
// ONE change vs r12: c/m mapping SWAPPED in both branches so consecutive blocks
// share the same B panel (B is the 51.4MB operand; A panels are tiny & L2-warm).
// GEMM1: idx 0..783, c0=(idx/2)*128, m0=(idx%2)*128 -> B1t panel read ~once not 2x.
// GEMM4: bb 0..3135, c0=(bb/16)*64, m0=(bb%16)*64 -> 16 adjacent blocks share B panel.
__global__ __launch_bounds__(256) void gemm14_kernel(
    const short* __restrict__ w1f, const short* __restrict__ dswb,
    const short* __restrict__ B1t,
    const float* __restrict__ alpha1, const float* __restrict__ bias1,
    bf16* __restrict__ h1, bf16* __restrict__ sc) {
    int blk = blockIdx.x;
    int t = threadIdx.x;
    int w = t >> 6, l = t & 63;
    int r0 = t >> 2;
    int kg = (t & 3) * 8;
    int wbase = w * 512;
    int lm = (l >> 4);
    int lc = l & 15;

    if (blk < 784) {
        // ======== GEMM1: 128x128, M=256, K=512, SP=784 ========
        __shared__ short As[128 * 32];
        __shared__ short Bs[128 * 32];
        const int SP = 784, M = 256, K = 512;
        int c0 = (blk / 2) * 128;      // B-panel-major: pairs of blocks share c0? no —
        int m0 = (blk % 2) * 128;      // adjacent blk (even,odd) share c0, differ m0
        int wm = (w >> 1) * 64, wn = (w & 1) * 64;
        size_t rowB0 = c0 + r0;
        size_t rowB1 = c0 + r0 + 64;

        float4v acc[4][4];
        #pragma unroll
        for (int i = 0; i < 4; i++)
            #pragma unroll
            for (int j = 0; j < 4; j++) acc[i][j] = (float4v)0.f;

        for (int k0 = 0; k0 < K; k0 += 32) {
            gload_lds16(w1f + (size_t)(m0 + r0) * K + k0 + kg,      &As[wbase]);
            gload_lds16(w1f + (size_t)(m0 + r0 + 64) * K + k0 + kg, &As[2048 + wbase]);
            gload_lds16(B1t + rowB0 * K + k0 + kg,                  &Bs[wbase]);
            gload_lds16(B1t + rowB1 * K + k0 + kg,                  &Bs[2048 + wbase]);
            __syncthreads();

            short8 af[4], bfr[4];
            #pragma unroll
            for (int i = 0; i < 4; i++)
                af[i] = *(const short8*)&As[(wm + i * 16 + lc) * 32 + lm * 8];
            #pragma unroll
            for (int j = 0; j < 4; j++)
                bfr[j] = *(const short8*)&Bs[(wn + j * 16 + lc) * 32 + lm * 8];
            #pragma unroll
            for (int i = 0; i < 4; i++)
                #pragma unroll
                for (int j = 0; j < 4; j++)
                    acc[i][j] = __builtin_amdgcn_mfma_f32_16x16x32_bf16(af[i], bfr[j], acc[i][j], 0, 0, 0);
            __syncthreads();
        }

        #pragma unroll
        for (int i = 0; i < 4; i++) {
            #pragma unroll
            for (int r = 0; r < 4; r++) {
                int m = m0 + wm + i * 16 + lm * 4 + r;
                float a = alpha1[m];
                float bia = bias1[m];
                #pragma unroll
                for (int j = 0; j < 4; j++) {
                    int c = c0 + wn + j * 16 + lc;
                    int n = c / SP;
                    int p = c - n * SP;
                    h1[((size_t)n * M + m) * SP + p] = __float2bfloat16((acc[i][j][r] + bia) * a);
                }
            }
        }
    } else {
        // ======== GEMM4: 64x64 + stride-2 remap, M=1024, K=512 ========
        __shared__ short As4[64 * 32];
        __shared__ short Bs4[64 * 32];
        const int SP = 196, M = 1024, K = 512;
        int bb = blk - 784;
        int c0 = (bb / 16) * 64;       // 16 adjacent blocks share the B panel
        int m0 = (bb % 16) * 64;
        int wm = (w >> 1) * 32, wn = (w & 1) * 32;

        int c = c0 + r0;
        int nn = c / 196, pp = c - nn * 196;
        int oh = pp / 14, ow = pp - oh * 14;
        size_t rowB = (size_t)nn * 784 + oh * 56 + ow * 2;

        float4v acc[2][2];
        #pragma unroll
        for (int i = 0; i < 2; i++)
            #pragma unroll
            for (int j = 0; j < 2; j++) acc[i][j] = (float4v)0.f;

        for (int k0 = 0; k0 < K; k0 += 32) {
            gload_lds16(dswb + (size_t)(m0 + r0) * K + k0 + kg, &As4[wbase]);
            gload_lds16(B1t + rowB * K + k0 + kg,               &Bs4[wbase]);
            __syncthreads();

            short8 af[2], bfr[2];
            #pragma unroll
            for (int i = 0; i < 2; i++)
                af[i] = *(const short8*)&As4[(wm + i * 16 + lc) * 32 + lm * 8];
            #pragma unroll
            for (int j = 0; j < 2; j++)
                bfr[j] = *(const short8*)&Bs4[(wn + j * 16 + lc) * 32 + lm * 8];
            #pragma unroll
            for (int i = 0; i < 2; i++)
                #pragma unroll
                for (int j = 0; j < 2; j++)
                    acc[i][j] = __builtin_amdgcn_mfma_f32_16x16x32_bf16(af[i], bfr[j], acc[i][j], 0, 0, 0);
            __syncthreads();
        }

        #pragma unroll
        for (int i = 0; i < 2; i++) {
            #pragma unroll
            for (int r = 0; r < 4; r++) {
                int m = m0 + wm + i * 16 + lm * 4 + r;
                #pragma unroll
                for (int j = 0; j < 2; j++) {
                    int cc = c0 + wn + j * 16 + lc;
                    int n = cc / SP;
                    int p = cc - n * SP;
                    sc[((size_t)n * M + m) * SP + p] = __float2bfloat16(acc[i][j][r]);
                }
            }
        }
    }
}

// ---------------- MFMA GEMM (128x128 tile, BK=32, 4 waves, 4x4 16x16x32) ----------------
// K-loop VERBATIM from round-7 (verified). Used for GEMM3 only. FUSE epilogue
// computes ds-BN scale/shift inline from raw stats.
template <int SP, typename TOut, bool HAS_ALPHA, bool FUSE, bool HAS_BIAS, bool BREMAP>
__global__ __launch_bounds__(256) void gemm_kernel(
    const short* __restrict__ A, const short* __restrict__ Bt,
    const float* __restrict__ alpha, TOut* __restrict__ out,
    int M, int K,
    const bf16* __restrict__ scv,
    const float* __restrict__ fsum, const float* __restrict__ fsq,
    const float* __restrict__ fg, const float* __restrict__ fb, float fcnt,
    const float* __restrict__ bias) {
    __shared__ short As[128 * 32];
    __shared__ short Bs[128 * 32];
    int t = threadIdx.x;
    int c0 = blockIdx.x * 128;
    int m0 = blockIdx.y * 128;
    int w = t >> 6, l = t & 63;
    int wm = (w >> 1) * 64, wn = (w & 1) * 64;

    int r0 = t >> 2;
    int kg = (t & 3) * 8;
    int wbase = w * 512;

    size_t rowB0, rowB1;
    if (BREMAP) {
        int c = c0 + r0;
        int nn = c / 196, pp = c - nn * 196;
        int oh = pp / 14, ow = pp - oh * 14;
        rowB0 = (size_t)nn * 784 + oh * 56 + ow * 2;
        c += 64;
        nn = c / 196; pp = c - nn * 196;
        oh = pp / 14; ow = pp - oh * 14;
        rowB1 = (size_t)nn * 784 + oh * 56 + ow * 2;
    } else {
        rowB0 = c0 + r0;
        rowB1 = c0 + r0 + 64;
    }

    float4v acc[4][4];
    #pragma unroll
    for (int i = 0; i < 4; i++)
        #pragma unroll
        for (int j = 0; j < 4; j++) acc[i][j] = (float4v)0.f;

    int lm = (l >> 4);
    int lc = l & 15;

    for (int k0 = 0; k0 < K; k0 += 32) {
        gload_lds16(A + (size_t)(m0 + r0) * K + k0 + kg,      &As[wbase]);
        gload_lds16(A + (size_t)(m0 + r0 + 64) * K + k0 + kg, &As[2048 + wbase]);
        gload_lds16(Bt + rowB0 * K + k0 + kg,                 &Bs[wbase]);
        gload_lds16(Bt + rowB1 * K + k0 + kg,                 &Bs[2048 + wbase]);
        __syncthreads();

        short8 af[4], bfr[4];
        #pragma unroll
        for (int i = 0; i < 4; i++)
            af[i] = *(const short8*)&As[(wm + i * 16 + lc) * 32 + lm * 8];
        #pragma unroll
        for (int j = 0; j < 4; j++)
            bfr[j] = *(const short8*)&Bs[(wn + j * 16 + lc) * 32 + lm * 8];
        #pragma unroll
        for (int i = 0; i < 4; i++)
            #pragma unroll
            for (int j = 0; j < 4; j++)
                acc[i][j] = __builtin_amdgcn_mfma_f32_16x16x32_bf16(af[i], bfr[j], acc[i][j], 0, 0, 0);
        __syncthreads();
    }

    #pragma unroll
    for (int i = 0; i < 4; i++) {
        #pragma unroll
        for (int r = 0; r < 4; r++) {
            int m = m0 + wm + i * 16 + lm * 4 + r;
            float a = HAS_ALPHA ? alpha[m] : 1.f;
            float bia = HAS_BIAS ? bias[m] : 0.f;
            float fsc = 0.f, fsh = 0.f;
            if (FUSE) bn_fin(fsum[m], fsq[m], fg[m], fb[m], fcnt, fsc, fsh);
            #pragma unroll
            for (int j = 0; j < 4; j++) {
                int c = c0 + wn + j * 16 + lc;
                int n = c / SP;
                int p = c - n * SP;
                size_t idx = ((size_t)n * M + m) * SP + p;
                float v = acc[i][j][r];
                if (HAS_BIAS) v += bia;
                if (HAS_ALPHA) v *= a;
                if (FUSE) v += toF(scv[idx]) * fsc + fsh;
                stF(&out[idx], v);
            }
        }
    }
}

// ---------------- GEMM2-dedicated kernel: 64x64 tile (784 blocks) ----------------
// Verbatim round-7 body.
__global__ __launch_bounds__(256) void gemm2_kernel(
    const short* __restrict__ A, const short* __restrict__ Bt,
    const float* __restrict__ alpha, bf16* __restrict__ out,
    int M, int K) {
    constexpr int SP = 196;
    __shared__ short As[64 * 32];
    __shared__ short Bs[64 * 32];
    int t = threadIdx.x;
    int c0 = blockIdx.x * 64;
    int m0 = blockIdx.y * 64;
    int w = t >> 6, l = t & 63;
    int wm = (w >> 1) * 32, wn = (w & 1) * 32;

    int r0 = t >> 2;          // 0..63
    int kg = (t & 3) * 8;     // 0,8,16,24
    int wbase = w * 512;

    float4v acc[2][2];
    #pragma unroll
    for (int i = 0; i < 2; i++)
        #pragma unroll
        for (int j = 0; j < 2; j++) acc[i][j] = (float4v)0.f;

    int lm = (l >> 4);
    int lc = l & 15;

    for (int k0 = 0; k0 < K; k0 += 32) {
        gload_lds16(A + (size_t)(m0 + r0) * K + k0 + kg,  &As[wbase]);
        gload_lds16(Bt + (size_t)(c0 + r0) * K + k0 + kg, &Bs[wbase]);
        __syncthreads();

        short8 af[2], bfr[2];
        #pragma unroll
        for (int i = 0; i < 2; i++)
            af[i] = *(const short8*)&As[(wm + i * 16 + lc) * 32 + lm * 8];
        #pragma unroll
        for (int j = 0; j < 2; j++)
            bfr[j] = *(const short8*)&Bs[(wn + j * 16 + lc) * 32 + lm * 8];
        #pragma unroll
        for (int i = 0; i < 2; i++)
            #pragma unroll
            for (int j = 0; j < 2; j++)
                acc[i][j] = __builtin_amdgcn_mfma_f32_16x16x32_bf16(af[i], bfr[j], acc[i][j], 0, 0, 0);
        __syncthreads();
    }

    #pragma unroll
    for (int i = 0; i < 2; i++) {
        #pragma unroll
        for (int r = 0; r < 4; r++) {
            int m = m0 + wm + i * 16 + lm * 4 + r;
            float a = alpha[m];
            #pragma unroll
            for (int j = 0; j < 2; j++) {
                int c = c0 + wn + j * 16 + lc;
                int n = c / SP;
                int p = c - n * SP;
                out[((size_t)n * M + m) * SP + p] = __float2bfloat16(acc[i][j][r] * a);
            }
        }
    }
}

extern "C" void kernel_launch(void* const* d_in, const int* in_sizes, int n_in,
                              void* d_out, int out_size, void* d_ws, size_t ws_size,
                              hipStream_t stream) {
    const float* x      = (const float*)d_in[0];   // (64,512,28,28)
    const float* bn1_g  = (const float*)d_in[1];
    const float* bn1_b  = (const float*)d_in[2];
    const float* w1     = (const float*)d_in[3];   // (256,512,1,1)
    const float* bn2_g  = (const float*)d_in[4];
    const float* bn2_b  = (const float*)d_in[5];
    const float* w2     = (const float*)d_in[6];   // (256,256,3,3)
    const float* bn3_g  = (const float*)d_in[7];
    const float* bn3_b  = (const float*)d_in[8];
    const float* w3     = (const float*)d_in[9];   // (1024,256,1,1)
    const float* ds_w   = (const float*)d_in[10];  // (1024,512,1,1) NOT ternarized
    const float* dbn_g  = (const float*)d_in[11];
    const float* dbn_b  = (const float*)d_in[12];
    float* out = (float*)d_out;

    const int N = 64, C1 = 512, C2 = 256, C3 = 1024;
    const int SP1 = 784, SP2 = 196;
    const int NT1 = N * SP1;   // 50176
    const int NT2 = N * SP2;   // 12544

    // ---- workspace layout ----
    char* wsb = (char*)d_ws;
    size_t off = 0;
    auto alloc = [&](size_t bytes) { char* p = wsb + off; off += (bytes + 255) & ~(size_t)255; return p; };

    char* pool = alloc((size_t)NT2 * 2304 * 2);   // 57.8 MB: B1t (51.4) / B2t (57.8) / B3t (6.4) time-share
    short* B1t = (short*)pool;                    // raw bf16(x)^T; live until gemm14
    short* B2t = (short*)pool;                    // created by im2col AFTER gemm14
    short* B3t = (short*)pool;                    // created after B2t is dead
    bf16*  sc  = (bf16*)alloc((size_t)N * C3 * SP2 * 2);  // 25.7 MB, own region

    bf16* h1 = (bf16*)alloc((size_t)N * C2 * SP1 * 2);
    bf16* h2 = (bf16*)alloc((size_t)N * C2 * SP2 * 2);
    short* w1t  = (short*)alloc((size_t)C2 * C1 * 2);
    short* w1f  = (short*)alloc((size_t)C2 * C1 * 2);   // scale-folded w1
    short* w2t  = (short*)alloc((size_t)C2 * C2 * 9 * 2);
    short* w3t  = (short*)alloc((size_t)C3 * C2 * 2);
    short* dswb = (short*)alloc((size_t)C3 * C1 * 2);
    float* alpha1 = (float*)alloc(C2 * 4);
    float* alpha2 = (float*)alloc(C2 * 4);
    float* alpha3 = (float*)alloc(C3 * 4);
    float* bias1  = (float*)alloc(C2 * 4);
    float* acc_base = (float*)alloc((size_t)(C1 + C2 + C2 + C3) * 2 * 4);
    float* sum1 = acc_base;            float* sq1 = sum1 + C1;
    float* sum2 = sq1 + C1;            float* sq2 = sum2 + C2;
    float* sum3 = sq2 + C2;            float* sq3 = sum3 + C2;
    float* sumd = sq3 + C2;            float* sqd = sumd + C3;
    (void)ws_size; (void)in_sizes; (void)n_in; (void)out_size;

    // 1) zero BN accumulators
    hipMemsetAsync(acc_base, 0, (size_t)(C1 + C2 + C2 + C3) * 2 * 4, stream);

    // 2) merged prep: weights (ternarize+cast) || stats_transpose (x -> B1t + bn1 stats)
    prep_kernel<<<10240, 256, 0, stream>>>(w1, w2, w3, ds_w, w1t, w2t, w3t, dswb,
                                           alpha1, alpha2, alpha3, x, B1t, sum1, sq1);

    // 3) foldbias (+inline bn1 finalize): w1f, bias1
    foldbias_kernel<<<C2, 256, 0, stream>>>(w1t, sum1, sq1, bn1_g, bn1_b,
                                            w1f, bias1, C1, (float)(N * SP1));

    // 4) merged GEMM1 || GEMM4 (contiguous ranges, B-panel-major mapping): h1, sc
    gemm14_kernel<<<3920, 256, 0, stream>>>(w1f, dswb, B1t, alpha1, bias1, h1, sc);

    // 5) dual BN stats: sc -> sumd/sqd, h1 -> sum2/sq2
    bn_sum_dual_kernel<<<dim3(C3 + C2, 8), 256, 0, stream>>>(
        sc, h1, sumd, sqd, sum2, sq2);

    // 6) im2col (+inline bn2 finalize) -> B2t (overwrites pool; B1t dead)
    im2col_tiled_kernel<<<dim3(16, 64), 256, 0, stream>>>(
        h1, sum2, sq2, bn2_g, bn2_b, (float)(N * SP1), B2t);

    // 7) GEMM2 (64x64): h2 = alpha2 * (w2t . B2t^T)   M=256 K=2304
    gemm2_kernel<<<dim3(NT2 / 64, C2 / 64), 256, 0, stream>>>(
        w2t, B2t, alpha2, h2, C2, C2 * 9);

    // 8) bn3 stats on h2
    bn_sum_kernel<bf16, 4><<<dim3(C2, 4), 256, 0, stream>>>(h2, sum3, sq3, C2, SP2, N, 4);

    // 9) B3t = bn3(h2)^T (+inline bn3 finalize)
    {
        dim3 grid((SP2 + 63) / 64, C2 / 64, N);
        affine_transpose_bf16_kernel<<<grid, 256, 0, stream>>>(
            h2, sum3, sq3, bn3_g, bn3_b, (float)(N * SP2), B3t, C2, SP2);
    }

    // 10) GEMM3 with fused residual (+inline ds-bn finalize):
    //     out = alpha3*(w3t . B3t^T) + sc*scaled + shiftd
    gemm_kernel<196, float, true, true, false, false>
        <<<dim3(NT2 / 128, C3 / 128), 256, 0, stream>>>(
        w3t, B3t, alpha3, out, C3, C2,
        sc, sumd, sqd, dbn_g, dbn_b, (float)(N * SP2), nullptr);
}

// Round 18
// 383.746 us; speedup vs baseline: 1.0631x; 1.0347x over previous
//
#include <hip/hip_runtime.h>
#include <hip/hip_bf16.h>
#include <math.h>

#define EPS 1e-5f

typedef __hip_bfloat16 bf16;
typedef short short8 __attribute__((ext_vector_type(8)));
typedef float float4v __attribute__((ext_vector_type(4)));

__device__ __forceinline__ float toF(float v) { return v; }
__device__ __forceinline__ float toF(bf16 v) { return __bfloat162float(v); }
__device__ __forceinline__ void stF(float* p, float v) { *p = v; }
__device__ __forceinline__ void stF(bf16* p, float v) { *p = __float2bfloat16(v); }
__device__ __forceinline__ short f2bs(float v) {
    bf16 b = __float2bfloat16(v);
    return *reinterpret_cast<short*>(&b);
}
__device__ __forceinline__ float bs2f(short s) {
    unsigned u = ((unsigned)(unsigned short)s) << 16;
    return __uint_as_float(u);
}

// direct global->LDS DMA, 16B per lane. LDS dest: wave-uniform base + lane*16.
__device__ __forceinline__ void gload_lds16(const short* g, short* l) {
    __builtin_amdgcn_global_load_lds(
        (const __attribute__((address_space(1))) unsigned int*)g,
        (__attribute__((address_space(3))) unsigned int*)l, 16, 0, 0);
}

// BN finalize formula (identical to the removed bn_finalize_kernel)
__device__ __forceinline__ void bn_fin(float sum, float sq, float g, float b, float cnt,
                                       float& scale, float& shift) {
    float mean = sum / cnt;
    float var = fmaxf(sq / cnt - mean * mean, 0.f);
    float r = rsqrtf(var + EPS);
    scale = g * r;
    shift = b - mean * scale;
}

// ---------------- block reduction (blockDim.x == 256) ----------------
__device__ __forceinline__ float block_reduce_sum(float v) {
    __shared__ float s[256];
    int t = threadIdx.x;
    s[t] = v;
    __syncthreads();
    #pragma unroll
    for (int st = 128; st > 0; st >>= 1) {
        if (t < st) s[t] += s[t + st];
        __syncthreads();
    }
    float r = s[0];
    __syncthreads();
    return r;
}

// ---------------- ternarize body (device fn, uniform per block) ----------------
__device__ __forceinline__ void ternarize_body(const float* __restrict__ w,
                                               short* __restrict__ wt,
                                               float* __restrict__ alpha, int K, int f) {
    const float* wf = w + (size_t)f * K;
    short* wtf = wt + (size_t)f * K;

    float s = 0.f;
    for (int i = threadIdx.x; i < K; i += 256) s += fabsf(wf[i]);
    float total = block_reduce_sum(s);
    float delta = 0.7f * total / (float)K;

    float sm = 0.f, cm = 0.f;
    for (int i = threadIdx.x; i < K; i += 256) {
        float a = fabsf(wf[i]);
        if (a > delta) { sm += a; cm += 1.f; }
    }
    sm = block_reduce_sum(sm);
    cm = block_reduce_sum(cm);
    if (threadIdx.x == 0) alpha[f] = sm / (cm + 1e-8f);

    for (int i = threadIdx.x; i < K; i += 256) {
        float v = wf[i];
        float a = fabsf(v);
        wtf[i] = (a > delta) ? ((v > 0.f) ? (short)0x3F80 : (short)0xBF80) : (short)0;
    }
}

// ---------------- merged prep kernel: weights (ternarize+cast) PARALLEL WITH
// stats_transpose (x -> B1t + bn1 stats). Block-range dispatch (validated r11/r12).
__global__ __launch_bounds__(256) void prep_kernel(
    const float* __restrict__ w1, const float* __restrict__ w2,
    const float* __restrict__ w3, const float* __restrict__ ds_w,
    short* __restrict__ w1t, short* __restrict__ w2t, short* __restrict__ w3t,
    short* __restrict__ dswb,
    float* __restrict__ alpha1, float* __restrict__ alpha2, float* __restrict__ alpha3,
    const float* __restrict__ x, short* __restrict__ B1t,
    float* __restrict__ sum1, float* __restrict__ sq1) {
    int b = blockIdx.x;
    if (b < 256)        ternarize_body(w1, w1t, alpha1, 512, b);
    else if (b < 512)   ternarize_body(w2, w2t, alpha2, 2304, b - 256);
    else if (b < 1536)  ternarize_body(w3, w3t, alpha3, 256, b - 512);
    else if (b < 3584) {
        int i = (b - 1536) * 256 + threadIdx.x;
        if (i < 1024 * 512) dswb[i] = f2bs(ds_w[i]);
    } else {
        // ---- stats_transpose body (verbatim r11, C=512 SP=784), flattened grid ----
        const int C = 512, SP = 784;
        __shared__ short tile[64][66];
        __shared__ float rs[4][64], rq[4][64];
        int bb = b - 3584;
        int n = bb / 104;             // grid.z = 64
        int ci0 = ((bb / 13) % 8) * 64;
        int p0 = (bb % 13) * 64;
        int t = threadIdx.x;
        int tx = t & 63;
        int ty4 = t >> 6;  // 0..3

        {
            int p4 = t & 15;
            int cib = t >> 4;
            int p = p0 + p4 * 4;
            bool pok = (p + 3) < SP;
            #pragma unroll
            for (int it = 0; it < 4; it++) {
                int ci = cib + it * 16;
                float4 q;
                if (pok) q = *(const float4*)(x + ((size_t)n * C + ci0 + ci) * SP + p);
                else     q = make_float4(0.f, 0.f, 0.f, 0.f);
                tile[p4 * 4 + 0][ci] = f2bs(q.x);
                tile[p4 * 4 + 1][ci] = f2bs(q.y);
                tile[p4 * 4 + 2][ci] = f2bs(q.z);
                tile[p4 * 4 + 3][ci] = f2bs(q.w);
            }
        }
        __syncthreads();

        {
            int seg = t & 7;
            #pragma unroll
            for (int it = 0; it < 2; it++) {
                int pl = (t >> 3) + it * 32;
                int pw = p0 + pl;
                if (pw < SP) {
                    short v[8];
                    #pragma unroll
                    for (int u = 0; u < 8; u++) v[u] = tile[pl][seg * 8 + u];
                    *(int4*)(B1t + ((size_t)n * SP + pw) * C + ci0 + seg * 8) = *(int4*)v;
                }
            }
        }

        float s = 0.f, s2 = 0.f;
        #pragma unroll
        for (int r = 0; r < 16; r++) {
            int pl = ty4 + r * 4;
            int pw = p0 + pl;
            if (pw < SP) {
                float v = bs2f(tile[pl][tx]);
                s += v; s2 += v * v;
            }
        }
        rs[ty4][tx] = s; rq[ty4][tx] = s2;
        __syncthreads();
        if (ty4 == 0) {
            float ts = rs[0][tx] + rs[1][tx] + rs[2][tx] + rs[3][tx];
            float tq = rq[0][tx] + rq[1][tx] + rq[2][tx] + rq[3][tx];
            atomicAdd(&sum1[ci0 + tx], ts);
            atomicAdd(&sq1[ci0 + tx], tq);
        }
    }
}

// ---------------- foldbias (+inline bn1 finalize): w1f = t*scale1, bias1 = t.shift1 ----------------
__global__ void foldbias_kernel(const short* __restrict__ wt,
                                const float* __restrict__ sum, const float* __restrict__ sq,
                                const float* __restrict__ g, const float* __restrict__ b,
                                short* __restrict__ wf, float* __restrict__ bias,
                                int K, float cnt) {
    int f = blockIdx.x;
    float s = 0.f;
    for (int k = threadIdx.x; k < K; k += blockDim.x) {
        float scale, shift;
        bn_fin(sum[k], sq[k], g[k], b[k], cnt, scale, shift);
        float tv = bs2f(wt[(size_t)f * K + k]);
        wf[(size_t)f * K + k] = f2bs(tv * scale);
        s += tv * shift;
    }
    s = block_reduce_sum(s);
    if (threadIdx.x == 0) bias[f] = s;
}

// ---------------- BN stats phase A (h2 only now) ----------------
template <typename T, int VEC>
__global__ __launch_bounds__(256) void bn_sum_kernel(
    const T* __restrict__ src, float* __restrict__ sum, float* __restrict__ sq,
    int C, int spatial, int N, int splits) {
    int c = blockIdx.x;
    int vpc = spatial / VEC;
    int total = N * vpc;
    float s = 0.f, s2 = 0.f;
    for (int v = blockIdx.y * 256 + threadIdx.x; v < total; v += splits * 256) {
        int n = v / vpc;
        int i = v - n * vpc;
        const T* p = src + ((size_t)n * C + c) * spatial + i * VEC;
        short tmp[VEC];
        if (VEC == 8) *(int4*)tmp = *(const int4*)p;
        else          *(int2*)tmp = *(const int2*)p;
        #pragma unroll
        for (int k = 0; k < VEC; k++) { float vv = bs2f(tmp[k]); s += vv; s2 += vv * vv; }
    }
    s = block_reduce_sum(s);
    s2 = block_reduce_sum(s2);
    if (threadIdx.x == 0) {
        atomicAdd(&sum[c], s);
        atomicAdd(&sq[c], s2);
    }
}

// ---------------- dual BN stats: sc (C=1024, sp=196, VEC4) + h1 (C=256, sp=784, VEC8) ----------------
template <int VEC>
__device__ __forceinline__ void bn_sum_body(const bf16* __restrict__ src, int C, int c,
                                            int spatial, int N, int splits,
                                            float* __restrict__ sum, float* __restrict__ sq) {
    int vpc = spatial / VEC;
    int total = N * vpc;
    float s = 0.f, s2 = 0.f;
    for (int v = blockIdx.y * 256 + threadIdx.x; v < total; v += splits * 256) {
        int n = v / vpc;
        int i = v - n * vpc;
        const bf16* p = src + ((size_t)n * C + c) * spatial + i * VEC;
        short tmp[VEC];
        if (VEC == 8) *(int4*)tmp = *(const int4*)p;
        else          *(int2*)tmp = *(const int2*)p;
        #pragma unroll
        for (int k = 0; k < VEC; k++) { float vv = bs2f(tmp[k]); s += vv; s2 += vv * vv; }
    }
    s = block_reduce_sum(s);
    s2 = block_reduce_sum(s2);
    if (threadIdx.x == 0) {
        atomicAdd(&sum[c], s);
        atomicAdd(&sq[c], s2);
    }
}

__global__ __launch_bounds__(256) void bn_sum_dual_kernel(
    const bf16* __restrict__ scv, const bf16* __restrict__ h1,
    float* __restrict__ sumd, float* __restrict__ sqd,
    float* __restrict__ sum2, float* __restrict__ sq2) {
    int cb = blockIdx.x;
    if (cb < 1024) bn_sum_body<4>(scv, 1024, cb, 196, 64, 8, sumd, sqd);
    else           bn_sum_body<8>(h1, 256, cb - 1024, 784, 64, 8, sum2, sq2);
}

// ---------------- affine transpose (bf16, VMEM-wide, +inline bn3 finalize): h2 -> B3t ----------------
__global__ __launch_bounds__(256) void affine_transpose_bf16_kernel(
    const bf16* __restrict__ in,
    const float* __restrict__ sum, const float* __restrict__ sq,
    const float* __restrict__ g, const float* __restrict__ b, float cnt,
    short* __restrict__ Bt, int C, int SP) {
    __shared__ short tile[64][66];
    int n = blockIdx.z;
    int ci0 = blockIdx.y * 64;
    int p0 = blockIdx.x * 64;
    int t = threadIdx.x;

    {
        int p4 = t & 15;
        int cib = t >> 4;
        int p = p0 + p4 * 4;
        bool pok = (p + 3) < SP;          // SP%4==0
        #pragma unroll
        for (int it = 0; it < 4; it++) {
            int ci = cib + it * 16;
            short v[4] = {0, 0, 0, 0};
            if (pok) *(int2*)v = *(const int2*)(in + ((size_t)n * C + ci0 + ci) * SP + p);
            float sc, sh;
            bn_fin(sum[ci0 + ci], sq[ci0 + ci], g[ci0 + ci], b[ci0 + ci], cnt, sc, sh);
            #pragma unroll
            for (int j = 0; j < 4; j++)
                tile[p4 * 4 + j][ci] = f2bs(bs2f(v[j]) * sc + sh);
        }
    }
    __syncthreads();

    {
        int seg = t & 7;
        #pragma unroll
        for (int it = 0; it < 2; it++) {
            int pl = (t >> 3) + it * 32;
            int pw = p0 + pl;
            if (pw < SP) {
                short v[8];
                #pragma unroll
                for (int u = 0; u < 8; u++) v[u] = tile[pl][seg * 8 + u];
                *(int4*)(Bt + ((size_t)n * SP + pw) * C + ci0 + seg * 8) = *(int4*)v;
            }
        }
    }
}

// ---------------- LDS-tiled im2col (+inline bn2 finalize) for conv2 (3x3 s2 p1) ----------------
__global__ __launch_bounds__(256) void im2col_tiled_kernel(
    const bf16* __restrict__ h1,
    const float* __restrict__ sum, const float* __restrict__ sq,
    const float* __restrict__ g, const float* __restrict__ b, float cnt,
    short* __restrict__ B2t) {
    __shared__ short tile[16][784];   // 25 KB
    int cb = blockIdx.x;              // 0..15 (16-channel slab)
    int n  = blockIdx.y;              // 0..63
    int ci0 = cb * 16;
    int t = threadIdx.x;

    for (int v = t; v < 16 * 98; v += 256) {
        int ci = v / 98;
        int i8 = (v - ci * 98) * 8;
        short tmp[8];
        *(int4*)tmp = *(const int4*)(h1 + ((size_t)n * 256 + ci0 + ci) * 784 + i8);
        float sc, sh;
        bn_fin(sum[ci0 + ci], sq[ci0 + ci], g[ci0 + ci], b[ci0 + ci], cnt, sc, sh);
        short ov[8];
        #pragma unroll
        for (int k = 0; k < 8; k++) ov[k] = f2bs(bs2f(tmp[k]) * sc + sh);
        *(int4*)&tile[ci][i8] = *(int4*)ov;
    }
    __syncthreads();

    for (int w = t; w < 196 * 18; w += 256) {
        int p = w / 18, seg = w - p * 18;
        int oh = p / 14, ow = p - oh * 14;
        int kbase = seg * 8;
        short vals[8];
        #pragma unroll
        for (int u = 0; u < 8; u++) {
            int kk = kbase + u;
            int ci_l = kk / 9;
            int rr = kk - ci_l * 9;
            int kh = rr / 3, kw = rr - kh * 3;
            int ih = 2 * oh - 1 + kh;
            int iw = 2 * ow - 1 + kw;
            vals[u] = ((unsigned)ih < 28u && (unsigned)iw < 28u)
                          ? tile[ci_l][ih * 28 + iw] : (short)0;
        }
        *(int4*)(B2t + ((size_t)(n * 196 + p)) * 2304 + ci0 * 9 + kbase) = *(int4*)vals;
    }
}

// ---------------- merged GEMM1 || GEMM4, SAFE 2-phase double-buffered pipeline ----------------
// r17 (= r16 resubmit; r16 was an infra failure). r15's counted-vmcnt pipeline
// RACED (vmcnt counts compiler-scheduled global loads too). Safe variant: issue
// tile k+1's global_load_lds BEFORE computing tile k from the other buffer, then
// ONE __syncthreads() per iteration (lowers to vmcnt(0)+lgkmcnt(0)+s_barrier —
// full drain, immune to compiler-inserted loads; no inline asm). HBM latency
// overlaps the compute phase; drain pays only the residual. Mappings/epilogues
// verbatim r14 (B-panel-major, 397.1us verified).
__global__ __launch_bounds__(256) void gemm14_kernel(
    const short* __restrict__ w1f, const short* __restrict__ dswb,
    const short* __restrict__ B1t,
    const float* __restrict__ alpha1, const float* __restrict__ bias1,
    bf16* __restrict__ h1, bf16* __restrict__ sc) {
    __shared__ short lds[16384];   // 32 KB union (G1 dbuf: As0|As1|Bs0|Bs1 4096 ea; G4 uses 8192)
    int blk = blockIdx.x;
    int t = threadIdx.x;
    int w = t >> 6, l = t & 63;
    int r0 = t >> 2;
    int kg = (t & 3) * 8;
    int wbase = w * 512;
    int lm = (l >> 4);
    int lc = l & 15;

    if (blk < 784) {
        // ======== GEMM1: 128x128, M=256, K=512, SP=784, 16 K-tiles ========
        const int SP = 784, M = 256, K = 512;
        int c0 = (blk / 2) * 128;
        int m0 = (blk % 2) * 128;
        int wm = (w >> 1) * 64, wn = (w & 1) * 64;
        size_t rowB0 = c0 + r0;
        size_t rowB1 = c0 + r0 + 64;

        float4v acc[4][4];
        #pragma unroll
        for (int i = 0; i < 4; i++)
            #pragma unroll
            for (int j = 0; j < 4; j++) acc[i][j] = (float4v)0.f;

        // prologue: stage tile 0 into buf 0; full drain
        gload_lds16(w1f + (size_t)(m0 + r0) * K + kg,      &lds[wbase]);
        gload_lds16(w1f + (size_t)(m0 + r0 + 64) * K + kg, &lds[2048 + wbase]);
        gload_lds16(B1t + rowB0 * K + kg,                  &lds[8192 + wbase]);
        gload_lds16(B1t + rowB1 * K + kg,                  &lds[8192 + 2048 + wbase]);
        __syncthreads();

        for (int it = 0; it < 16; it++) {
            int cur = it & 1;
            int curA = cur * 4096, curB = 8192 + cur * 4096;
            if (it < 15) {
                int nxtA = (cur ^ 1) * 4096, nxtB = 8192 + (cur ^ 1) * 4096;
                int k1 = (it + 1) * 32;
                gload_lds16(w1f + (size_t)(m0 + r0) * K + k1 + kg,      &lds[nxtA + wbase]);
                gload_lds16(w1f + (size_t)(m0 + r0 + 64) * K + k1 + kg, &lds[nxtA + 2048 + wbase]);
                gload_lds16(B1t + rowB0 * K + k1 + kg,                  &lds[nxtB + wbase]);
                gload_lds16(B1t + rowB1 * K + k1 + kg,                  &lds[nxtB + 2048 + wbase]);
            }

            short8 af[4], bfr[4];
            #pragma unroll
            for (int i = 0; i < 4; i++)
                af[i] = *(const short8*)&lds[curA + (wm + i * 16 + lc) * 32 + lm * 8];
            #pragma unroll
            for (int j = 0; j < 4; j++)
                bfr[j] = *(const short8*)&lds[curB + (wn + j * 16 + lc) * 32 + lm * 8];
            #pragma unroll
            for (int i = 0; i < 4; i++)
                #pragma unroll
                for (int j = 0; j < 4; j++)
                    acc[i][j] = __builtin_amdgcn_mfma_f32_16x16x32_bf16(af[i], bfr[j], acc[i][j], 0, 0, 0);
            __syncthreads();   // next tile landed (vmcnt 0) AND all reads of cur done
        }

        #pragma unroll
        for (int i = 0; i < 4; i++) {
            #pragma unroll
            for (int r = 0; r < 4; r++) {
                int m = m0 + wm + i * 16 + lm * 4 + r;
                float a = alpha1[m];
                float bia = bias1[m];
                #pragma unroll
                for (int j = 0; j < 4; j++) {
                    int c = c0 + wn + j * 16 + lc;
                    int n = c / SP;
                    int p = c - n * SP;
                    h1[((size_t)n * M + m) * SP + p] = __float2bfloat16((acc[i][j][r] + bia) * a);
                }
            }
        }
    } else {
        // ======== GEMM4: 64x64 + stride-2 remap, M=1024, K=512, 16 K-tiles ========
        const int SP = 196, M = 1024, K = 512;
        int bb = blk - 784;
        int c0 = (bb / 16) * 64;
        int m0 = (bb % 16) * 64;
        int wm = (w >> 1) * 32, wn = (w & 1) * 32;

        int c = c0 + r0;
        int nn = c / 196, pp = c - nn * 196;
        int oh = pp / 14, ow = pp - oh * 14;
        size_t rowB = (size_t)nn * 784 + oh * 56 + ow * 2;

        float4v acc[2][2];
        #pragma unroll
        for (int i = 0; i < 2; i++)
            #pragma unroll
            for (int j = 0; j < 2; j++) acc[i][j] = (float4v)0.f;

        // layout: As0 [0,2048) As1 [2048,4096) Bs0 [4096,6144) Bs1 [6144,8192)
        gload_lds16(dswb + (size_t)(m0 + r0) * K + kg, &lds[wbase]);
        gload_lds16(B1t + rowB * K + kg,               &lds[4096 + wbase]);
        __syncthreads();

        for (int it = 0; it < 16; it++) {
            int cur = it & 1;
            int curA = cur * 2048, curB = 4096 + cur * 2048;
            if (it < 15) {
                int nxtA = (cur ^ 1) * 2048, nxtB = 4096 + (cur ^ 1) * 2048;
                int k1 = (it + 1) * 32;
                gload_lds16(dswb + (size_t)(m0 + r0) * K + k1 + kg, &lds[nxtA + wbase]);
                gload_lds16(B1t + rowB * K + k1 + kg,               &lds[nxtB + wbase]);
            }

            short8 af[2], bfr[2];
            #pragma unroll
            for (int i = 0; i < 2; i++)
                af[i] = *(const short8*)&lds[curA + (wm + i * 16 + lc) * 32 + lm * 8];
            #pragma unroll
            for (int j = 0; j < 2; j++)
                bfr[j] = *(const short8*)&lds[curB + (wn + j * 16 + lc) * 32 + lm * 8];
            #pragma unroll
            for (int i = 0; i < 2; i++)
                #pragma unroll
                for (int j = 0; j < 2; j++)
                    acc[i][j] = __builtin_amdgcn_mfma_f32_16x16x32_bf16(af[i], bfr[j], acc[i][j], 0, 0, 0);
            __syncthreads();
        }

        #pragma unroll
        for (int i = 0; i < 2; i++) {
            #pragma unroll
            for (int r = 0; r < 4; r++) {
                int m = m0 + wm + i * 16 + lm * 4 + r;
                #pragma unroll
                for (int j = 0; j < 2; j++) {
                    int cc = c0 + wn + j * 16 + lc;
                    int n = cc / SP;
                    int p = cc - n * SP;
                    sc[((size_t)n * M + m) * SP + p] = __float2bfloat16(acc[i][j][r]);
                }
            }
        }
    }
}

// ---------------- MFMA GEMM (128x128 tile, BK=32, 4 waves, 4x4 16x16x32) ----------------
// K-loop VERBATIM from round-7 (verified). Used for GEMM3 only. FUSE epilogue
// computes ds-BN scale/shift inline from raw stats.
template <int SP, typename TOut, bool HAS_ALPHA, bool FUSE, bool HAS_BIAS, bool BREMAP>
__global__ __launch_bounds__(256) void gemm_kernel(
    const short* __restrict__ A, const short* __restrict__ Bt,
    const float* __restrict__ alpha, TOut* __restrict__ out,
    int M, int K,
    const bf16* __restrict__ scv,
    const float* __restrict__ fsum, const float* __restrict__ fsq,
    const float* __restrict__ fg, const float* __restrict__ fb, float fcnt,
    const float* __restrict__ bias) {
    __shared__ short As[128 * 32];
    __shared__ short Bs[128 * 32];
    int t = threadIdx.x;
    int c0 = blockIdx.x * 128;
    int m0 = blockIdx.y * 128;
    int w = t >> 6, l = t & 63;
    int wm = (w >> 1) * 64, wn = (w & 1) * 64;

    int r0 = t >> 2;
    int kg = (t & 3) * 8;
    int wbase = w * 512;

    size_t rowB0, rowB1;
    if (BREMAP) {
        int c = c0 + r0;
        int nn = c / 196, pp = c - nn * 196;
        int oh = pp / 14, ow = pp - oh * 14;
        rowB0 = (size_t)nn * 784 + oh * 56 + ow * 2;
        c += 64;
        nn = c / 196; pp = c - nn * 196;
        oh = pp / 14; ow = pp - oh * 14;
        rowB1 = (size_t)nn * 784 + oh * 56 + ow * 2;
    } else {
        rowB0 = c0 + r0;
        rowB1 = c0 + r0 + 64;
    }

    float4v acc[4][4];
    #pragma unroll
    for (int i = 0; i < 4; i++)
        #pragma unroll
        for (int j = 0; j < 4; j++) acc[i][j] = (float4v)0.f;

    int lm = (l >> 4);
    int lc = l & 15;

    for (int k0 = 0; k0 < K; k0 += 32) {
        gload_lds16(A + (size_t)(m0 + r0) * K + k0 + kg,      &As[wbase]);
        gload_lds16(A + (size_t)(m0 + r0 + 64) * K + k0 + kg, &As[2048 + wbase]);
        gload_lds16(Bt + rowB0 * K + k0 + kg,                 &Bs[wbase]);
        gload_lds16(Bt + rowB1 * K + k0 + kg,                 &Bs[2048 + wbase]);
        __syncthreads();

        short8 af[4], bfr[4];
        #pragma unroll
        for (int i = 0; i < 4; i++)
            af[i] = *(const short8*)&As[(wm + i * 16 + lc) * 32 + lm * 8];
        #pragma unroll
        for (int j = 0; j < 4; j++)
            bfr[j] = *(const short8*)&Bs[(wn + j * 16 + lc) * 32 + lm * 8];
        #pragma unroll
        for (int i = 0; i < 4; i++)
            #pragma unroll
            for (int j = 0; j < 4; j++)
                acc[i][j] = __builtin_amdgcn_mfma_f32_16x16x32_bf16(af[i], bfr[j], acc[i][j], 0, 0, 0);
        __syncthreads();
    }

    #pragma unroll
    for (int i = 0; i < 4; i++) {
        #pragma unroll
        for (int r = 0; r < 4; r++) {
            int m = m0 + wm + i * 16 + lm * 4 + r;
            float a = HAS_ALPHA ? alpha[m] : 1.f;
            float bia = HAS_BIAS ? bias[m] : 0.f;
            float fsc = 0.f, fsh = 0.f;
            if (FUSE) bn_fin(fsum[m], fsq[m], fg[m], fb[m], fcnt, fsc, fsh);
            #pragma unroll
            for (int j = 0; j < 4; j++) {
                int c = c0 + wn + j * 16 + lc;
                int n = c / SP;
                int p = c - n * SP;
                size_t idx = ((size_t)n * M + m) * SP + p;
                float v = acc[i][j][r];
                if (HAS_BIAS) v += bia;
                if (HAS_ALPHA) v *= a;
                if (FUSE) v += toF(scv[idx]) * fsc + fsh;
                stF(&out[idx], v);
            }
        }
    }
}

// ---------------- GEMM2: 64x64 tile, SAFE 2-phase double-buffered (72 K-tiles) ----------------
__global__ __launch_bounds__(256) void gemm2_kernel(
    const short* __restrict__ A, const short* __restrict__ Bt,
    const float* __restrict__ alpha, bf16* __restrict__ out,
    int M, int K) {
    constexpr int SP = 196;
    __shared__ short lds[8192];   // As0 [0,2048) As1 [2048,4096) Bs0 [4096,6144) Bs1 [6144,8192)
    int t = threadIdx.x;
    int c0 = blockIdx.x * 64;
    int m0 = blockIdx.y * 64;
    int w = t >> 6, l = t & 63;
    int wm = (w >> 1) * 32, wn = (w & 1) * 32;

    int r0 = t >> 2;          // 0..63
    int kg = (t & 3) * 8;     // 0,8,16,24
    int wbase = w * 512;

    float4v acc[2][2];
    #pragma unroll
    for (int i = 0; i < 2; i++)
        #pragma unroll
        for (int j = 0; j < 2; j++) acc[i][j] = (float4v)0.f;

    int lm = (l >> 4);
    int lc = l & 15;
    int NT = K / 32;

    gload_lds16(A + (size_t)(m0 + r0) * K + kg,  &lds[wbase]);
    gload_lds16(Bt + (size_t)(c0 + r0) * K + kg, &lds[4096 + wbase]);
    __syncthreads();

    for (int it = 0; it < NT; it++) {
        int cur = it & 1;
        int curA = cur * 2048, curB = 4096 + cur * 2048;
        if (it < NT - 1) {
            int nxtA = (cur ^ 1) * 2048, nxtB = 4096 + (cur ^ 1) * 2048;
            int k1 = (it + 1) * 32;
            gload_lds16(A + (size_t)(m0 + r0) * K + k1 + kg,  &lds[nxtA + wbase]);
            gload_lds16(Bt + (size_t)(c0 + r0) * K + k1 + kg, &lds[nxtB + wbase]);
        }

        short8 af[2], bfr[2];
        #pragma unroll
        for (int i = 0; i < 2; i++)
            af[i] = *(const short8*)&lds[curA + (wm + i * 16 + lc) * 32 + lm * 8];
        #pragma unroll
        for (int j = 0; j < 2; j++)
            bfr[j] = *(const short8*)&lds[curB + (wn + j * 16 + lc) * 32 + lm * 8];
        #pragma unroll
        for (int i = 0; i < 2; i++)
            #pragma unroll
            for (int j = 0; j < 2; j++)
                acc[i][j] = __builtin_amdgcn_mfma_f32_16x16x32_bf16(af[i], bfr[j], acc[i][j], 0, 0, 0);
        __syncthreads();
    }

    #pragma unroll
    for (int i = 0; i < 2; i++) {
        #pragma unroll
        for (int r = 0; r < 4; r++) {
            int m = m0 + wm + i * 16 + lm * 4 + r;
            float a = alpha[m];
            #pragma unroll
            for (int j = 0; j < 2; j++) {
                int c = c0 + wn + j * 16 + lc;
                int n = c / SP;
                int p = c - n * SP;
                out[((size_t)n * M + m) * SP + p] = __float2bfloat16(acc[i][j][r] * a);
            }
        }
    }
}

extern "C" void kernel_launch(void* const* d_in, const int* in_sizes, int n_in,
                              void* d_out, int out_size, void* d_ws, size_t ws_size,
                              hipStream_t stream) {
    const float* x      = (const float*)d_in[0];   // (64,512,28,28)
    const float* bn1_g  = (const float*)d_in[1];
    const float* bn1_b  = (const float*)d_in[2];
    const float* w1     = (const float*)d_in[3];   // (256,512,1,1)
    const float* bn2_g  = (const float*)d_in[4];
    const float* bn2_b  = (const float*)d_in[5];
    const float* w2     = (const float*)d_in[6];   // (256,256,3,3)
    const float* bn3_g  = (const float*)d_in[7];
    const float* bn3_b  = (const float*)d_in[8];
    const float* w3     = (const float*)d_in[9];   // (1024,256,1,1)
    const float* ds_w   = (const float*)d_in[10];  // (1024,512,1,1) NOT ternarized
    const float* dbn_g  = (const float*)d_in[11];
    const float* dbn_b  = (const float*)d_in[12];
    float* out = (float*)d_out;

    const int N = 64, C1 = 512, C2 = 256, C3 = 1024;
    const int SP1 = 784, SP2 = 196;
    const int NT1 = N * SP1;   // 50176
    const int NT2 = N * SP2;   // 12544

    // ---- workspace layout ----
    char* wsb = (char*)d_ws;
    size_t off = 0;
    auto alloc = [&](size_t bytes) { char* p = wsb + off; off += (bytes + 255) & ~(size_t)255; return p; };

    char* pool = alloc((size_t)NT2 * 2304 * 2);   // 57.8 MB: B1t (51.4) / B2t (57.8) / B3t (6.4) time-share
    short* B1t = (short*)pool;                    // raw bf16(x)^T; live until gemm14
    short* B2t = (short*)pool;                    // created by im2col AFTER gemm14
    short* B3t = (short*)pool;                    // created after B2t is dead
    bf16*  sc  = (bf16*)alloc((size_t)N * C3 * SP2 * 2);  // 25.7 MB, own region

    bf16* h1 = (bf16*)alloc((size_t)N * C2 * SP1 * 2);
    bf16* h2 = (bf16*)alloc((size_t)N * C2 * SP2 * 2);
    short* w1t  = (short*)alloc((size_t)C2 * C1 * 2);
    short* w1f  = (short*)alloc((size_t)C2 * C1 * 2);   // scale-folded w1
    short* w2t  = (short*)alloc((size_t)C2 * C2 * 9 * 2);
    short* w3t  = (short*)alloc((size_t)C3 * C2 * 2);
    short* dswb = (short*)alloc((size_t)C3 * C1 * 2);
    float* alpha1 = (float*)alloc(C2 * 4);
    float* alpha2 = (float*)alloc(C2 * 4);
    float* alpha3 = (float*)alloc(C3 * 4);
    float* bias1  = (float*)alloc(C2 * 4);
    float* acc_base = (float*)alloc((size_t)(C1 + C2 + C2 + C3) * 2 * 4);
    float* sum1 = acc_base;            float* sq1 = sum1 + C1;
    float* sum2 = sq1 + C1;            float* sq2 = sum2 + C2;
    float* sum3 = sq2 + C2;            float* sq3 = sum3 + C2;
    float* sumd = sq3 + C2;            float* sqd = sumd + C3;
    (void)ws_size; (void)in_sizes; (void)n_in; (void)out_size;

    // 1) zero BN accumulators
    hipMemsetAsync(acc_base, 0, (size_t)(C1 + C2 + C2 + C3) * 2 * 4, stream);

    // 2) merged prep: weights (ternarize+cast) || stats_transpose (x -> B1t + bn1 stats)
    prep_kernel<<<10240, 256, 0, stream>>>(w1, w2, w3, ds_w, w1t, w2t, w3t, dswb,
                                           alpha1, alpha2, alpha3, x, B1t, sum1, sq1);

    // 3) foldbias (+inline bn1 finalize): w1f, bias1
    foldbias_kernel<<<C2, 256, 0, stream>>>(w1t, sum1, sq1, bn1_g, bn1_b,
                                            w1f, bias1, C1, (float)(N * SP1));

    // 4) merged GEMM1 || GEMM4 (safe 2-phase dbuf pipeline): h1, sc
    gemm14_kernel<<<3920, 256, 0, stream>>>(w1f, dswb, B1t, alpha1, bias1, h1, sc);

    // 5) dual BN stats: sc -> sumd/sqd, h1 -> sum2/sq2
    bn_sum_dual_kernel<<<dim3(C3 + C2, 8), 256, 0, stream>>>(
        sc, h1, sumd, sqd, sum2, sq2);

    // 6) im2col (+inline bn2 finalize) -> B2t (overwrites pool; B1t dead)
    im2col_tiled_kernel<<<dim3(16, 64), 256, 0, stream>>>(
        h1, sum2, sq2, bn2_g, bn2_b, (float)(N * SP1), B2t);

    // 7) GEMM2 (64x64, safe 2-phase dbuf): h2 = alpha2 * (w2t . B2t^T)   M=256 K=2304
    gemm2_kernel<<<dim3(NT2 / 64, C2 / 64), 256, 0, stream>>>(
        w2t, B2t, alpha2, h2, C2, C2 * 9);

    // 8) bn3 stats on h2
    bn_sum_kernel<bf16, 4><<<dim3(C2, 4), 256, 0, stream>>>(h2, sum3, sq3, C2, SP2, N, 4);

    // 9) B3t = bn3(h2)^T (+inline bn3 finalize)
    {
        dim3 grid((SP2 + 63) / 64, C2 / 64, N);
        affine_transpose_bf16_kernel<<<grid, 256, 0, stream>>>(
            h2, sum3, sq3, bn3_g, bn3_b, (float)(N * SP2), B3t, C2, SP2);
    }

    // 10) GEMM3 with fused residual (+inline ds-bn finalize):
    //     out = alpha3*(w3t . B3t^T) + sc*scaled + shiftd
    gemm_kernel<196, float, true, true, false, false>
        <<<dim3(NT2 / 128, C3 / 128), 256, 0, stream>>>(
        w3t, B3t, alpha3, out, C3, C2,
        sc, sumd, sqd, dbn_g, dbn_b, (float)(N * SP2), nullptr);
}

// Round 19
// 383.558 us; speedup vs baseline: 1.0637x; 1.0005x over previous
//
#include <hip/hip_runtime.h>
#include <hip/hip_bf16.h>
#include <math.h>

#define EPS 1e-5f

typedef __hip_bfloat16 bf16;
typedef short short8 __attribute__((ext_vector_type(8)));
typedef float float4v __attribute__((ext_vector_type(4)));

__device__ __forceinline__ float toF(float v) { return v; }
__device__ __forceinline__ float toF(bf16 v) { return __bfloat162float(v); }
__device__ __forceinline__ void stF(float* p, float v) { *p = v; }
__device__ __forceinline__ void stF(bf16* p, float v) { *p = __float2bfloat16(v); }
__device__ __forceinline__ short f2bs(float v) {
    bf16 b = __float2bfloat16(v);
    return *reinterpret_cast<short*>(&b);
}
__device__ __forceinline__ float bs2f(short s) {
    unsigned u = ((unsigned)(unsigned short)s) << 16;
    return __uint_as_float(u);
}

// direct global->LDS DMA, 16B per lane. LDS dest: wave-uniform base + lane*16.
__device__ __forceinline__ void gload_lds16(const short* g, short* l) {
    __builtin_amdgcn_global_load_lds(
        (const __attribute__((address_space(1))) unsigned int*)g,
        (__attribute__((address_space(3))) unsigned int*)l, 16, 0, 0);
}

// BN finalize formula (identical to the removed bn_finalize_kernel)
__device__ __forceinline__ void bn_fin(float sum, float sq, float g, float b, float cnt,
                                       float& scale, float& shift) {
    float mean = sum / cnt;
    float var = fmaxf(sq / cnt - mean * mean, 0.f);
    float r = rsqrtf(var + EPS);
    scale = g * r;
    shift = b - mean * scale;
}

// ---------------- block reduction (blockDim.x == 256) ----------------
__device__ __forceinline__ float block_reduce_sum(float v) {
    __shared__ float s[256];
    int t = threadIdx.x;
    s[t] = v;
    __syncthreads();
    #pragma unroll
    for (int st = 128; st > 0; st >>= 1) {
        if (t < st) s[t] += s[t + st];
        __syncthreads();
    }
    float r = s[0];
    __syncthreads();
    return r;
}

// ---------------- ternarize body (device fn, uniform per block) ----------------
__device__ __forceinline__ void ternarize_body(const float* __restrict__ w,
                                               short* __restrict__ wt,
                                               float* __restrict__ alpha, int K, int f) {
    const float* wf = w + (size_t)f * K;
    short* wtf = wt + (size_t)f * K;

    float s = 0.f;
    for (int i = threadIdx.x; i < K; i += 256) s += fabsf(wf[i]);
    float total = block_reduce_sum(s);
    float delta = 0.7f * total / (float)K;

    float sm = 0.f, cm = 0.f;
    for (int i = threadIdx.x; i < K; i += 256) {
        float a = fabsf(wf[i]);
        if (a > delta) { sm += a; cm += 1.f; }
    }
    sm = block_reduce_sum(sm);
    cm = block_reduce_sum(cm);
    if (threadIdx.x == 0) alpha[f] = sm / (cm + 1e-8f);

    for (int i = threadIdx.x; i < K; i += 256) {
        float v = wf[i];
        float a = fabsf(v);
        wtf[i] = (a > delta) ? ((v > 0.f) ? (short)0x3F80 : (short)0xBF80) : (short)0;
    }
}

// ---------------- merged prep kernel: weights (ternarize+cast) PARALLEL WITH
// stats_transpose (x -> B1t + bn1 stats). Block-range dispatch (validated r11/r12).
__global__ __launch_bounds__(256) void prep_kernel(
    const float* __restrict__ w1, const float* __restrict__ w2,
    const float* __restrict__ w3, const float* __restrict__ ds_w,
    short* __restrict__ w1t, short* __restrict__ w2t, short* __restrict__ w3t,
    short* __restrict__ dswb,
    float* __restrict__ alpha1, float* __restrict__ alpha2, float* __restrict__ alpha3,
    const float* __restrict__ x, short* __restrict__ B1t,
    float* __restrict__ sum1, float* __restrict__ sq1) {
    int b = blockIdx.x;
    if (b < 256)        ternarize_body(w1, w1t, alpha1, 512, b);
    else if (b < 512)   ternarize_body(w2, w2t, alpha2, 2304, b - 256);
    else if (b < 1536)  ternarize_body(w3, w3t, alpha3, 256, b - 512);
    else if (b < 3584) {
        int i = (b - 1536) * 256 + threadIdx.x;
        if (i < 1024 * 512) dswb[i] = f2bs(ds_w[i]);
    } else {
        // ---- stats_transpose body (verbatim r11, C=512 SP=784), flattened grid ----
        const int C = 512, SP = 784;
        __shared__ short tile[64][66];
        __shared__ float rs[4][64], rq[4][64];
        int bb = b - 3584;
        int n = bb / 104;             // grid.z = 64
        int ci0 = ((bb / 13) % 8) * 64;
        int p0 = (bb % 13) * 64;
        int t = threadIdx.x;
        int tx = t & 63;
        int ty4 = t >> 6;  // 0..3

        {
            int p4 = t & 15;
            int cib = t >> 4;
            int p = p0 + p4 * 4;
            bool pok = (p + 3) < SP;
            #pragma unroll
            for (int it = 0; it < 4; it++) {
                int ci = cib + it * 16;
                float4 q;
                if (pok) q = *(const float4*)(x + ((size_t)n * C + ci0 + ci) * SP + p);
                else     q = make_float4(0.f, 0.f, 0.f, 0.f);
                tile[p4 * 4 + 0][ci] = f2bs(q.x);
                tile[p4 * 4 + 1][ci] = f2bs(q.y);
                tile[p4 * 4 + 2][ci] = f2bs(q.z);
                tile[p4 * 4 + 3][ci] = f2bs(q.w);
            }
        }
        __syncthreads();

        {
            int seg = t & 7;
            #pragma unroll
            for (int it = 0; it < 2; it++) {
                int pl = (t >> 3) + it * 32;
                int pw = p0 + pl;
                if (pw < SP) {
                    short v[8];
                    #pragma unroll
                    for (int u = 0; u < 8; u++) v[u] = tile[pl][seg * 8 + u];
                    *(int4*)(B1t + ((size_t)n * SP + pw) * C + ci0 + seg * 8) = *(int4*)v;
                }
            }
        }

        float s = 0.f, s2 = 0.f;
        #pragma unroll
        for (int r = 0; r < 16; r++) {
            int pl = ty4 + r * 4;
            int pw = p0 + pl;
            if (pw < SP) {
                float v = bs2f(tile[pl][tx]);
                s += v; s2 += v * v;
            }
        }
        rs[ty4][tx] = s; rq[ty4][tx] = s2;
        __syncthreads();
        if (ty4 == 0) {
            float ts = rs[0][tx] + rs[1][tx] + rs[2][tx] + rs[3][tx];
            float tq = rq[0][tx] + rq[1][tx] + rq[2][tx] + rq[3][tx];
            atomicAdd(&sum1[ci0 + tx], ts);
            atomicAdd(&sq1[ci0 + tx], tq);
        }
    }
}

// ---------------- foldbias (+inline bn1 finalize): w1f = t*scale1, bias1 = t.shift1 ----------------
__global__ void foldbias_kernel(const short* __restrict__ wt,
                                const float* __restrict__ sum, const float* __restrict__ sq,
                                const float* __restrict__ g, const float* __restrict__ b,
                                short* __restrict__ wf, float* __restrict__ bias,
                                int K, float cnt) {
    int f = blockIdx.x;
    float s = 0.f;
    for (int k = threadIdx.x; k < K; k += blockDim.x) {
        float scale, shift;
        bn_fin(sum[k], sq[k], g[k], b[k], cnt, scale, shift);
        float tv = bs2f(wt[(size_t)f * K + k]);
        wf[(size_t)f * K + k] = f2bs(tv * scale);
        s += tv * shift;
    }
    s = block_reduce_sum(s);
    if (threadIdx.x == 0) bias[f] = s;
}

// ---------------- BN stats phase A (h2 only now) ----------------
template <typename T, int VEC>
__global__ __launch_bounds__(256) void bn_sum_kernel(
    const T* __restrict__ src, float* __restrict__ sum, float* __restrict__ sq,
    int C, int spatial, int N, int splits) {
    int c = blockIdx.x;
    int vpc = spatial / VEC;
    int total = N * vpc;
    float s = 0.f, s2 = 0.f;
    for (int v = blockIdx.y * 256 + threadIdx.x; v < total; v += splits * 256) {
        int n = v / vpc;
        int i = v - n * vpc;
        const T* p = src + ((size_t)n * C + c) * spatial + i * VEC;
        short tmp[VEC];
        if (VEC == 8) *(int4*)tmp = *(const int4*)p;
        else          *(int2*)tmp = *(const int2*)p;
        #pragma unroll
        for (int k = 0; k < VEC; k++) { float vv = bs2f(tmp[k]); s += vv; s2 += vv * vv; }
    }
    s = block_reduce_sum(s);
    s2 = block_reduce_sum(s2);
    if (threadIdx.x == 0) {
        atomicAdd(&sum[c], s);
        atomicAdd(&sq[c], s2);
    }
}

// ---------------- dual BN stats: sc (C=1024, sp=196, VEC4) + h1 (C=256, sp=784, VEC8) ----------------
template <int VEC>
__device__ __forceinline__ void bn_sum_body(const bf16* __restrict__ src, int C, int c,
                                            int spatial, int N, int splits,
                                            float* __restrict__ sum, float* __restrict__ sq) {
    int vpc = spatial / VEC;
    int total = N * vpc;
    float s = 0.f, s2 = 0.f;
    for (int v = blockIdx.y * 256 + threadIdx.x; v < total; v += splits * 256) {
        int n = v / vpc;
        int i = v - n * vpc;
        const bf16* p = src + ((size_t)n * C + c) * spatial + i * VEC;
        short tmp[VEC];
        if (VEC == 8) *(int4*)tmp = *(const int4*)p;
        else          *(int2*)tmp = *(const int2*)p;
        #pragma unroll
        for (int k = 0; k < VEC; k++) { float vv = bs2f(tmp[k]); s += vv; s2 += vv * vv; }
    }
    s = block_reduce_sum(s);
    s2 = block_reduce_sum(s2);
    if (threadIdx.x == 0) {
        atomicAdd(&sum[c], s);
        atomicAdd(&sq[c], s2);
    }
}

__global__ __launch_bounds__(256) void bn_sum_dual_kernel(
    const bf16* __restrict__ scv, const bf16* __restrict__ h1,
    float* __restrict__ sumd, float* __restrict__ sqd,
    float* __restrict__ sum2, float* __restrict__ sq2) {
    int cb = blockIdx.x;
    if (cb < 1024) bn_sum_body<4>(scv, 1024, cb, 196, 64, 8, sumd, sqd);
    else           bn_sum_body<8>(h1, 256, cb - 1024, 784, 64, 8, sum2, sq2);
}

// ---------------- affine transpose (bf16, VMEM-wide, +inline bn3 finalize): h2 -> B3t ----------------
__global__ __launch_bounds__(256) void affine_transpose_bf16_kernel(
    const bf16* __restrict__ in,
    const float* __restrict__ sum, const float* __restrict__ sq,
    const float* __restrict__ g, const float* __restrict__ b, float cnt,
    short* __restrict__ Bt, int C, int SP) {
    __shared__ short tile[64][66];
    int n = blockIdx.z;
    int ci0 = blockIdx.y * 64;
    int p0 = blockIdx.x * 64;
    int t = threadIdx.x;

    {
        int p4 = t & 15;
        int cib = t >> 4;
        int p = p0 + p4 * 4;
        bool pok = (p + 3) < SP;          // SP%4==0
        #pragma unroll
        for (int it = 0; it < 4; it++) {
            int ci = cib + it * 16;
            short v[4] = {0, 0, 0, 0};
            if (pok) *(int2*)v = *(const int2*)(in + ((size_t)n * C + ci0 + ci) * SP + p);
            float sc, sh;
            bn_fin(sum[ci0 + ci], sq[ci0 + ci], g[ci0 + ci], b[ci0 + ci], cnt, sc, sh);
            #pragma unroll
            for (int j = 0; j < 4; j++)
                tile[p4 * 4 + j][ci] = f2bs(bs2f(v[j]) * sc + sh);
        }
    }
    __syncthreads();

    {
        int seg = t & 7;
        #pragma unroll
        for (int it = 0; it < 2; it++) {
            int pl = (t >> 3) + it * 32;
            int pw = p0 + pl;
            if (pw < SP) {
                short v[8];
                #pragma unroll
                for (int u = 0; u < 8; u++) v[u] = tile[pl][seg * 8 + u];
                *(int4*)(Bt + ((size_t)n * SP + pw) * C + ci0 + seg * 8) = *(int4*)v;
            }
        }
    }
}

// ---------------- LDS-tiled im2col (+inline bn2 finalize) for conv2 (3x3 s2 p1) ----------------
__global__ __launch_bounds__(256) void im2col_tiled_kernel(
    const bf16* __restrict__ h1,
    const float* __restrict__ sum, const float* __restrict__ sq,
    const float* __restrict__ g, const float* __restrict__ b, float cnt,
    short* __restrict__ B2t) {
    __shared__ short tile[16][784];   // 25 KB
    int cb = blockIdx.x;              // 0..15 (16-channel slab)
    int n  = blockIdx.y;              // 0..63
    int ci0 = cb * 16;
    int t = threadIdx.x;

    for (int v = t; v < 16 * 98; v += 256) {
        int ci = v / 98;
        int i8 = (v - ci * 98) * 8;
        short tmp[8];
        *(int4*)tmp = *(const int4*)(h1 + ((size_t)n * 256 + ci0 + ci) * 784 + i8);
        float sc, sh;
        bn_fin(sum[ci0 + ci], sq[ci0 + ci], g[ci0 + ci], b[ci0 + ci], cnt, sc, sh);
        short ov[8];
        #pragma unroll
        for (int k = 0; k < 8; k++) ov[k] = f2bs(bs2f(tmp[k]) * sc + sh);
        *(int4*)&tile[ci][i8] = *(int4*)ov;
    }
    __syncthreads();

    for (int w = t; w < 196 * 18; w += 256) {
        int p = w / 18, seg = w - p * 18;
        int oh = p / 14, ow = p - oh * 14;
        int kbase = seg * 8;
        short vals[8];
        #pragma unroll
        for (int u = 0; u < 8; u++) {
            int kk = kbase + u;
            int ci_l = kk / 9;
            int rr = kk - ci_l * 9;
            int kh = rr / 3, kw = rr - kh * 3;
            int ih = 2 * oh - 1 + kh;
            int iw = 2 * ow - 1 + kw;
            vals[u] = ((unsigned)ih < 28u && (unsigned)iw < 28u)
                          ? tile[ci_l][ih * 28 + iw] : (short)0;
        }
        *(int4*)(B2t + ((size_t)(n * 196 + p)) * 2304 + ci0 * 9 + kbase) = *(int4*)vals;
    }
}

// ---------------- merged GEMM1 || GEMM4, SAFE 2-phase double-buffered pipeline ----------------
// Verified r17 (383.7us): issue tile k+1's global_load_lds BEFORE computing tile k
// from the other buffer, ONE __syncthreads() per iteration (full drain — immune
// to compiler-inserted loads; no inline asm). Mappings/epilogues r14 B-panel-major.
__global__ __launch_bounds__(256) void gemm14_kernel(
    const short* __restrict__ w1f, const short* __restrict__ dswb,
    const short* __restrict__ B1t,
    const float* __restrict__ alpha1, const float* __restrict__ bias1,
    bf16* __restrict__ h1, bf16* __restrict__ sc) {
    __shared__ short lds[16384];   // 32 KB union (G1 dbuf: As0|As1|Bs0|Bs1 4096 ea; G4 uses 8192)
    int blk = blockIdx.x;
    int t = threadIdx.x;
    int w = t >> 6, l = t & 63;
    int r0 = t >> 2;
    int kg = (t & 3) * 8;
    int wbase = w * 512;
    int lm = (l >> 4);
    int lc = l & 15;

    if (blk < 784) {
        // ======== GEMM1: 128x128, M=256, K=512, SP=784, 16 K-tiles ========
        const int SP = 784, M = 256, K = 512;
        int c0 = (blk / 2) * 128;
        int m0 = (blk % 2) * 128;
        int wm = (w >> 1) * 64, wn = (w & 1) * 64;
        size_t rowB0 = c0 + r0;
        size_t rowB1 = c0 + r0 + 64;

        float4v acc[4][4];
        #pragma unroll
        for (int i = 0; i < 4; i++)
            #pragma unroll
            for (int j = 0; j < 4; j++) acc[i][j] = (float4v)0.f;

        // prologue: stage tile 0 into buf 0; full drain
        gload_lds16(w1f + (size_t)(m0 + r0) * K + kg,      &lds[wbase]);
        gload_lds16(w1f + (size_t)(m0 + r0 + 64) * K + kg, &lds[2048 + wbase]);
        gload_lds16(B1t + rowB0 * K + kg,                  &lds[8192 + wbase]);
        gload_lds16(B1t + rowB1 * K + kg,                  &lds[8192 + 2048 + wbase]);
        __syncthreads();

        for (int it = 0; it < 16; it++) {
            int cur = it & 1;
            int curA = cur * 4096, curB = 8192 + cur * 4096;
            if (it < 15) {
                int nxtA = (cur ^ 1) * 4096, nxtB = 8192 + (cur ^ 1) * 4096;
                int k1 = (it + 1) * 32;
                gload_lds16(w1f + (size_t)(m0 + r0) * K + k1 + kg,      &lds[nxtA + wbase]);
                gload_lds16(w1f + (size_t)(m0 + r0 + 64) * K + k1 + kg, &lds[nxtA + 2048 + wbase]);
                gload_lds16(B1t + rowB0 * K + k1 + kg,                  &lds[nxtB + wbase]);
                gload_lds16(B1t + rowB1 * K + k1 + kg,                  &lds[nxtB + 2048 + wbase]);
            }

            short8 af[4], bfr[4];
            #pragma unroll
            for (int i = 0; i < 4; i++)
                af[i] = *(const short8*)&lds[curA + (wm + i * 16 + lc) * 32 + lm * 8];
            #pragma unroll
            for (int j = 0; j < 4; j++)
                bfr[j] = *(const short8*)&lds[curB + (wn + j * 16 + lc) * 32 + lm * 8];
            #pragma unroll
            for (int i = 0; i < 4; i++)
                #pragma unroll
                for (int j = 0; j < 4; j++)
                    acc[i][j] = __builtin_amdgcn_mfma_f32_16x16x32_bf16(af[i], bfr[j], acc[i][j], 0, 0, 0);
            __syncthreads();   // next tile landed (vmcnt 0) AND all reads of cur done
        }

        #pragma unroll
        for (int i = 0; i < 4; i++) {
            #pragma unroll
            for (int r = 0; r < 4; r++) {
                int m = m0 + wm + i * 16 + lm * 4 + r;
                float a = alpha1[m];
                float bia = bias1[m];
                #pragma unroll
                for (int j = 0; j < 4; j++) {
                    int c = c0 + wn + j * 16 + lc;
                    int n = c / SP;
                    int p = c - n * SP;
                    h1[((size_t)n * M + m) * SP + p] = __float2bfloat16((acc[i][j][r] + bia) * a);
                }
            }
        }
    } else {
        // ======== GEMM4: 64x64 + stride-2 remap, M=1024, K=512, 16 K-tiles ========
        const int SP = 196, M = 1024, K = 512;
        int bb = blk - 784;
        int c0 = (bb / 16) * 64;
        int m0 = (bb % 16) * 64;
        int wm = (w >> 1) * 32, wn = (w & 1) * 32;

        int c = c0 + r0;
        int nn = c / 196, pp = c - nn * 196;
        int oh = pp / 14, ow = pp - oh * 14;
        size_t rowB = (size_t)nn * 784 + oh * 56 + ow * 2;

        float4v acc[2][2];
        #pragma unroll
        for (int i = 0; i < 2; i++)
            #pragma unroll
            for (int j = 0; j < 2; j++) acc[i][j] = (float4v)0.f;

        // layout: As0 [0,2048) As1 [2048,4096) Bs0 [4096,6144) Bs1 [6144,8192)
        gload_lds16(dswb + (size_t)(m0 + r0) * K + kg, &lds[wbase]);
        gload_lds16(B1t + rowB * K + kg,               &lds[4096 + wbase]);
        __syncthreads();

        for (int it = 0; it < 16; it++) {
            int cur = it & 1;
            int curA = cur * 2048, curB = 4096 + cur * 2048;
            if (it < 15) {
                int nxtA = (cur ^ 1) * 2048, nxtB = 4096 + (cur ^ 1) * 2048;
                int k1 = (it + 1) * 32;
                gload_lds16(dswb + (size_t)(m0 + r0) * K + k1 + kg, &lds[nxtA + wbase]);
                gload_lds16(B1t + rowB * K + k1 + kg,               &lds[nxtB + wbase]);
            }

            short8 af[2], bfr[2];
            #pragma unroll
            for (int i = 0; i < 2; i++)
                af[i] = *(const short8*)&lds[curA + (wm + i * 16 + lc) * 32 + lm * 8];
            #pragma unroll
            for (int j = 0; j < 2; j++)
                bfr[j] = *(const short8*)&lds[curB + (wn + j * 16 + lc) * 32 + lm * 8];
            #pragma unroll
            for (int i = 0; i < 2; i++)
                #pragma unroll
                for (int j = 0; j < 2; j++)
                    acc[i][j] = __builtin_amdgcn_mfma_f32_16x16x32_bf16(af[i], bfr[j], acc[i][j], 0, 0, 0);
            __syncthreads();
        }

        #pragma unroll
        for (int i = 0; i < 2; i++) {
            #pragma unroll
            for (int r = 0; r < 4; r++) {
                int m = m0 + wm + i * 16 + lm * 4 + r;
                #pragma unroll
                for (int j = 0; j < 2; j++) {
                    int cc = c0 + wn + j * 16 + lc;
                    int n = cc / SP;
                    int p = cc - n * SP;
                    sc[((size_t)n * M + m) * SP + p] = __float2bfloat16(acc[i][j][r]);
                }
            }
        }
    }
}

// ---------------- GEMM3: 128x128 tile, SAFE 2-phase dbuf (8 K-tiles) + fused residual ----------------
// r18: port the r17-verified pipeline to GEMM3 (last un-pipelined GEMM).
// LDS dbuf layout identical to gemm14-G1 (As0|As1|Bs0|Bs1, 8KB each = 32KB).
// Epilogue (alpha + inline ds-bn finalize + sc residual) verbatim r17.
__global__ __launch_bounds__(256) void gemm3_kernel(
    const short* __restrict__ A, const short* __restrict__ Bt,
    const float* __restrict__ alpha, float* __restrict__ out,
    int M, int K,
    const bf16* __restrict__ scv,
    const float* __restrict__ fsum, const float* __restrict__ fsq,
    const float* __restrict__ fg, const float* __restrict__ fb, float fcnt) {
    constexpr int SP = 196;
    __shared__ short lds[16384];   // As0 [0,4096) As1 [4096,8192) Bs0 [8192,12288) Bs1 [12288,16384)
    int t = threadIdx.x;
    int c0 = blockIdx.x * 128;
    int m0 = blockIdx.y * 128;
    int w = t >> 6, l = t & 63;
    int wm = (w >> 1) * 64, wn = (w & 1) * 64;

    int r0 = t >> 2;
    int kg = (t & 3) * 8;
    int wbase = w * 512;

    size_t rowB0 = c0 + r0;
    size_t rowB1 = c0 + r0 + 64;

    float4v acc[4][4];
    #pragma unroll
    for (int i = 0; i < 4; i++)
        #pragma unroll
        for (int j = 0; j < 4; j++) acc[i][j] = (float4v)0.f;

    int lm = (l >> 4);
    int lc = l & 15;
    int NT = K / 32;

    // prologue: stage tile 0 into buf 0
    gload_lds16(A + (size_t)(m0 + r0) * K + kg,      &lds[wbase]);
    gload_lds16(A + (size_t)(m0 + r0 + 64) * K + kg, &lds[2048 + wbase]);
    gload_lds16(Bt + rowB0 * K + kg,                 &lds[8192 + wbase]);
    gload_lds16(Bt + rowB1 * K + kg,                 &lds[8192 + 2048 + wbase]);
    __syncthreads();

    for (int it = 0; it < NT; it++) {
        int cur = it & 1;
        int curA = cur * 4096, curB = 8192 + cur * 4096;
        if (it < NT - 1) {
            int nxtA = (cur ^ 1) * 4096, nxtB = 8192 + (cur ^ 1) * 4096;
            int k1 = (it + 1) * 32;
            gload_lds16(A + (size_t)(m0 + r0) * K + k1 + kg,      &lds[nxtA + wbase]);
            gload_lds16(A + (size_t)(m0 + r0 + 64) * K + k1 + kg, &lds[nxtA + 2048 + wbase]);
            gload_lds16(Bt + rowB0 * K + k1 + kg,                 &lds[nxtB + wbase]);
            gload_lds16(Bt + rowB1 * K + k1 + kg,                 &lds[nxtB + 2048 + wbase]);
        }

        short8 af[4], bfr[4];
        #pragma unroll
        for (int i = 0; i < 4; i++)
            af[i] = *(const short8*)&lds[curA + (wm + i * 16 + lc) * 32 + lm * 8];
        #pragma unroll
        for (int j = 0; j < 4; j++)
            bfr[j] = *(const short8*)&lds[curB + (wn + j * 16 + lc) * 32 + lm * 8];
        #pragma unroll
        for (int i = 0; i < 4; i++)
            #pragma unroll
            for (int j = 0; j < 4; j++)
                acc[i][j] = __builtin_amdgcn_mfma_f32_16x16x32_bf16(af[i], bfr[j], acc[i][j], 0, 0, 0);
        __syncthreads();
    }

    #pragma unroll
    for (int i = 0; i < 4; i++) {
        #pragma unroll
        for (int r = 0; r < 4; r++) {
            int m = m0 + wm + i * 16 + lm * 4 + r;
            float a = alpha[m];
            float fsc, fsh;
            bn_fin(fsum[m], fsq[m], fg[m], fb[m], fcnt, fsc, fsh);
            #pragma unroll
            for (int j = 0; j < 4; j++) {
                int c = c0 + wn + j * 16 + lc;
                int n = c / SP;
                int p = c - n * SP;
                size_t idx = ((size_t)n * M + m) * SP + p;
                float v = acc[i][j][r] * a + toF(scv[idx]) * fsc + fsh;
                out[idx] = v;
            }
        }
    }
}

// ---------------- GEMM2: 64x64 tile, SAFE 2-phase double-buffered (72 K-tiles) ----------------
__global__ __launch_bounds__(256) void gemm2_kernel(
    const short* __restrict__ A, const short* __restrict__ Bt,
    const float* __restrict__ alpha, bf16* __restrict__ out,
    int M, int K) {
    constexpr int SP = 196;
    __shared__ short lds[8192];   // As0 [0,2048) As1 [2048,4096) Bs0 [4096,6144) Bs1 [6144,8192)
    int t = threadIdx.x;
    int c0 = blockIdx.x * 64;
    int m0 = blockIdx.y * 64;
    int w = t >> 6, l = t & 63;
    int wm = (w >> 1) * 32, wn = (w & 1) * 32;

    int r0 = t >> 2;          // 0..63
    int kg = (t & 3) * 8;     // 0,8,16,24
    int wbase = w * 512;

    float4v acc[2][2];
    #pragma unroll
    for (int i = 0; i < 2; i++)
        #pragma unroll
        for (int j = 0; j < 2; j++) acc[i][j] = (float4v)0.f;

    int lm = (l >> 4);
    int lc = l & 15;
    int NT = K / 32;

    gload_lds16(A + (size_t)(m0 + r0) * K + kg,  &lds[wbase]);
    gload_lds16(Bt + (size_t)(c0 + r0) * K + kg, &lds[4096 + wbase]);
    __syncthreads();

    for (int it = 0; it < NT; it++) {
        int cur = it & 1;
        int curA = cur * 2048, curB = 4096 + cur * 2048;
        if (it < NT - 1) {
            int nxtA = (cur ^ 1) * 2048, nxtB = 4096 + (cur ^ 1) * 2048;
            int k1 = (it + 1) * 32;
            gload_lds16(A + (size_t)(m0 + r0) * K + k1 + kg,  &lds[nxtA + wbase]);
            gload_lds16(Bt + (size_t)(c0 + r0) * K + k1 + kg, &lds[nxtB + wbase]);
        }

        short8 af[2], bfr[2];
        #pragma unroll
        for (int i = 0; i < 2; i++)
            af[i] = *(const short8*)&lds[curA + (wm + i * 16 + lc) * 32 + lm * 8];
        #pragma unroll
        for (int j = 0; j < 2; j++)
            bfr[j] = *(const short8*)&lds[curB + (wn + j * 16 + lc) * 32 + lm * 8];
        #pragma unroll
        for (int i = 0; i < 2; i++)
            #pragma unroll
            for (int j = 0; j < 2; j++)
                acc[i][j] = __builtin_amdgcn_mfma_f32_16x16x32_bf16(af[i], bfr[j], acc[i][j], 0, 0, 0);
        __syncthreads();
    }

    #pragma unroll
    for (int i = 0; i < 2; i++) {
        #pragma unroll
        for (int r = 0; r < 4; r++) {
            int m = m0 + wm + i * 16 + lm * 4 + r;
            float a = alpha[m];
            #pragma unroll
            for (int j = 0; j < 2; j++) {
                int c = c0 + wn + j * 16 + lc;
                int n = c / SP;
                int p = c - n * SP;
                out[((size_t)n * M + m) * SP + p] = __float2bfloat16(acc[i][j][r] * a);
            }
        }
    }
}

extern "C" void kernel_launch(void* const* d_in, const int* in_sizes, int n_in,
                              void* d_out, int out_size, void* d_ws, size_t ws_size,
                              hipStream_t stream) {
    const float* x      = (const float*)d_in[0];   // (64,512,28,28)
    const float* bn1_g  = (const float*)d_in[1];
    const float* bn1_b  = (const float*)d_in[2];
    const float* w1     = (const float*)d_in[3];   // (256,512,1,1)
    const float* bn2_g  = (const float*)d_in[4];
    const float* bn2_b  = (const float*)d_in[5];
    const float* w2     = (const float*)d_in[6];   // (256,256,3,3)
    const float* bn3_g  = (const float*)d_in[7];
    const float* bn3_b  = (const float*)d_in[8];
    const float* w3     = (const float*)d_in[9];   // (1024,256,1,1)
    const float* ds_w   = (const float*)d_in[10];  // (1024,512,1,1) NOT ternarized
    const float* dbn_g  = (const float*)d_in[11];
    const float* dbn_b  = (const float*)d_in[12];
    float* out = (float*)d_out;

    const int N = 64, C1 = 512, C2 = 256, C3 = 1024;
    const int SP1 = 784, SP2 = 196;
    const int NT1 = N * SP1;   // 50176
    const int NT2 = N * SP2;   // 12544

    // ---- workspace layout ----
    char* wsb = (char*)d_ws;
    size_t off = 0;
    auto alloc = [&](size_t bytes) { char* p = wsb + off; off += (bytes + 255) & ~(size_t)255; return p; };

    char* pool = alloc((size_t)NT2 * 2304 * 2);   // 57.8 MB: B1t (51.4) / B2t (57.8) / B3t (6.4) time-share
    short* B1t = (short*)pool;                    // raw bf16(x)^T; live until gemm14
    short* B2t = (short*)pool;                    // created by im2col AFTER gemm14
    short* B3t = (short*)pool;                    // created after B2t is dead
    bf16*  sc  = (bf16*)alloc((size_t)N * C3 * SP2 * 2);  // 25.7 MB, own region

    bf16* h1 = (bf16*)alloc((size_t)N * C2 * SP1 * 2);
    bf16* h2 = (bf16*)alloc((size_t)N * C2 * SP2 * 2);
    short* w1t  = (short*)alloc((size_t)C2 * C1 * 2);
    short* w1f  = (short*)alloc((size_t)C2 * C1 * 2);   // scale-folded w1
    short* w2t  = (short*)alloc((size_t)C2 * C2 * 9 * 2);
    short* w3t  = (short*)alloc((size_t)C3 * C2 * 2);
    short* dswb = (short*)alloc((size_t)C3 * C1 * 2);
    float* alpha1 = (float*)alloc(C2 * 4);
    float* alpha2 = (float*)alloc(C2 * 4);
    float* alpha3 = (float*)alloc(C3 * 4);
    float* bias1  = (float*)alloc(C2 * 4);
    float* acc_base = (float*)alloc((size_t)(C1 + C2 + C2 + C3) * 2 * 4);
    float* sum1 = acc_base;            float* sq1 = sum1 + C1;
    float* sum2 = sq1 + C1;            float* sq2 = sum2 + C2;
    float* sum3 = sq2 + C2;            float* sq3 = sum3 + C2;
    float* sumd = sq3 + C2;            float* sqd = sumd + C3;
    (void)ws_size; (void)in_sizes; (void)n_in; (void)out_size;

    // 1) zero BN accumulators
    hipMemsetAsync(acc_base, 0, (size_t)(C1 + C2 + C2 + C3) * 2 * 4, stream);

    // 2) merged prep: weights (ternarize+cast) || stats_transpose (x -> B1t + bn1 stats)
    prep_kernel<<<10240, 256, 0, stream>>>(w1, w2, w3, ds_w, w1t, w2t, w3t, dswb,
                                           alpha1, alpha2, alpha3, x, B1t, sum1, sq1);

    // 3) foldbias (+inline bn1 finalize): w1f, bias1
    foldbias_kernel<<<C2, 256, 0, stream>>>(w1t, sum1, sq1, bn1_g, bn1_b,
                                            w1f, bias1, C1, (float)(N * SP1));

    // 4) merged GEMM1 || GEMM4 (safe 2-phase dbuf pipeline): h1, sc
    gemm14_kernel<<<3920, 256, 0, stream>>>(w1f, dswb, B1t, alpha1, bias1, h1, sc);

    // 5) dual BN stats: sc -> sumd/sqd, h1 -> sum2/sq2
    bn_sum_dual_kernel<<<dim3(C3 + C2, 8), 256, 0, stream>>>(
        sc, h1, sumd, sqd, sum2, sq2);

    // 6) im2col (+inline bn2 finalize) -> B2t (overwrites pool; B1t dead)
    im2col_tiled_kernel<<<dim3(16, 64), 256, 0, stream>>>(
        h1, sum2, sq2, bn2_g, bn2_b, (float)(N * SP1), B2t);

    // 7) GEMM2 (64x64, safe 2-phase dbuf): h2 = alpha2 * (w2t . B2t^T)   M=256 K=2304
    gemm2_kernel<<<dim3(NT2 / 64, C2 / 64), 256, 0, stream>>>(
        w2t, B2t, alpha2, h2, C2, C2 * 9);

    // 8) bn3 stats on h2
    bn_sum_kernel<bf16, 4><<<dim3(C2, 4), 256, 0, stream>>>(h2, sum3, sq3, C2, SP2, N, 4);

    // 9) B3t = bn3(h2)^T (+inline bn3 finalize)
    {
        dim3 grid((SP2 + 63) / 64, C2 / 64, N);
        affine_transpose_bf16_kernel<<<grid, 256, 0, stream>>>(
            h2, sum3, sq3, bn3_g, bn3_b, (float)(N * SP2), B3t, C2, SP2);
    }

    // 10) GEMM3 (safe 2-phase dbuf, fused residual + inline ds-bn finalize):
    //     out = alpha3*(w3t . B3t^T) + sc*scaled + shiftd
    gemm3_kernel<<<dim3(NT2 / 128, C3 / 128), 256, 0, stream>>>(
        w3t, B3t, alpha3, out, C3, C2,
        sc, sumd, sqd, dbn_g, dbn_b, (float)(N * SP2));
}

// Round 20
// 370.348 us; speedup vs baseline: 1.1016x; 1.0357x over previous
//
#include <hip/hip_runtime.h>
#include <hip/hip_bf16.h>
#include <math.h>

#define EPS 1e-5f

typedef __hip_bfloat16 bf16;
typedef short short8 __attribute__((ext_vector_type(8)));
typedef float float4v __attribute__((ext_vector_type(4)));

__device__ __forceinline__ float toF(float v) { return v; }
__device__ __forceinline__ float toF(bf16 v) { return __bfloat162float(v); }
__device__ __forceinline__ void stF(float* p, float v) { *p = v; }
__device__ __forceinline__ void stF(bf16* p, float v) { *p = __float2bfloat16(v); }
__device__ __forceinline__ short f2bs(float v) {
    bf16 b = __float2bfloat16(v);
    return *reinterpret_cast<short*>(&b);
}
__device__ __forceinline__ float bs2f(short s) {
    unsigned u = ((unsigned)(unsigned short)s) << 16;
    return __uint_as_float(u);
}

// direct global->LDS DMA, 16B per lane. LDS dest: wave-uniform base + lane*16.
__device__ __forceinline__ void gload_lds16(const short* g, short* l) {
    __builtin_amdgcn_global_load_lds(
        (const __attribute__((address_space(1))) unsigned int*)g,
        (__attribute__((address_space(3))) unsigned int*)l, 16, 0, 0);
}

// BN finalize formula (identical to the removed bn_finalize_kernel)
__device__ __forceinline__ void bn_fin(float sum, float sq, float g, float b, float cnt,
                                       float& scale, float& shift) {
    float mean = sum / cnt;
    float var = fmaxf(sq / cnt - mean * mean, 0.f);
    float r = rsqrtf(var + EPS);
    scale = g * r;
    shift = b - mean * scale;
}

// ---------------- block reduction (blockDim.x == 256) ----------------
__device__ __forceinline__ float block_reduce_sum(float v) {
    __shared__ float s[256];
    int t = threadIdx.x;
    s[t] = v;
    __syncthreads();
    #pragma unroll
    for (int st = 128; st > 0; st >>= 1) {
        if (t < st) s[t] += s[t + st];
        __syncthreads();
    }
    float r = s[0];
    __syncthreads();
    return r;
}

// ---------------- ternarize body (device fn, uniform per block) ----------------
__device__ __forceinline__ void ternarize_body(const float* __restrict__ w,
                                               short* __restrict__ wt,
                                               float* __restrict__ alpha, int K, int f) {
    const float* wf = w + (size_t)f * K;
    short* wtf = wt + (size_t)f * K;

    float s = 0.f;
    for (int i = threadIdx.x; i < K; i += 256) s += fabsf(wf[i]);
    float total = block_reduce_sum(s);
    float delta = 0.7f * total / (float)K;

    float sm = 0.f, cm = 0.f;
    for (int i = threadIdx.x; i < K; i += 256) {
        float a = fabsf(wf[i]);
        if (a > delta) { sm += a; cm += 1.f; }
    }
    sm = block_reduce_sum(sm);
    cm = block_reduce_sum(cm);
    if (threadIdx.x == 0) alpha[f] = sm / (cm + 1e-8f);

    for (int i = threadIdx.x; i < K; i += 256) {
        float v = wf[i];
        float a = fabsf(v);
        wtf[i] = (a > delta) ? ((v > 0.f) ? (short)0x3F80 : (short)0xBF80) : (short)0;
    }
}

// ---------------- merged prep kernel: weights (ternarize+cast) PARALLEL WITH
// stats_transpose (x -> B1t + bn1 stats). Block-range dispatch (validated r11/r12).
__global__ __launch_bounds__(256) void prep_kernel(
    const float* __restrict__ w1, const float* __restrict__ w2,
    const float* __restrict__ w3, const float* __restrict__ ds_w,
    short* __restrict__ w1t, short* __restrict__ w2t, short* __restrict__ w3t,
    short* __restrict__ dswb,
    float* __restrict__ alpha1, float* __restrict__ alpha2, float* __restrict__ alpha3,
    const float* __restrict__ x, short* __restrict__ B1t,
    float* __restrict__ sum1, float* __restrict__ sq1) {
    int b = blockIdx.x;
    if (b < 256)        ternarize_body(w1, w1t, alpha1, 512, b);
    else if (b < 512)   ternarize_body(w2, w2t, alpha2, 2304, b - 256);
    else if (b < 1536)  ternarize_body(w3, w3t, alpha3, 256, b - 512);
    else if (b < 3584) {
        int i = (b - 1536) * 256 + threadIdx.x;
        if (i < 1024 * 512) dswb[i] = f2bs(ds_w[i]);
    } else {
        // ---- stats_transpose body (verbatim r11, C=512 SP=784), flattened grid ----
        const int C = 512, SP = 784;
        __shared__ short tile[64][66];
        __shared__ float rs[4][64], rq[4][64];
        int bb = b - 3584;
        int n = bb / 104;             // grid.z = 64
        int ci0 = ((bb / 13) % 8) * 64;
        int p0 = (bb % 13) * 64;
        int t = threadIdx.x;
        int tx = t & 63;
        int ty4 = t >> 6;  // 0..3

        {
            int p4 = t & 15;
            int cib = t >> 4;
            int p = p0 + p4 * 4;
            bool pok = (p + 3) < SP;
            #pragma unroll
            for (int it = 0; it < 4; it++) {
                int ci = cib + it * 16;
                float4 q;
                if (pok) q = *(const float4*)(x + ((size_t)n * C + ci0 + ci) * SP + p);
                else     q = make_float4(0.f, 0.f, 0.f, 0.f);
                tile[p4 * 4 + 0][ci] = f2bs(q.x);
                tile[p4 * 4 + 1][ci] = f2bs(q.y);
                tile[p4 * 4 + 2][ci] = f2bs(q.z);
                tile[p4 * 4 + 3][ci] = f2bs(q.w);
            }
        }
        __syncthreads();

        {
            int seg = t & 7;
            #pragma unroll
            for (int it = 0; it < 2; it++) {
                int pl = (t >> 3) + it * 32;
                int pw = p0 + pl;
                if (pw < SP) {
                    short v[8];
                    #pragma unroll
                    for (int u = 0; u < 8; u++) v[u] = tile[pl][seg * 8 + u];
                    *(int4*)(B1t + ((size_t)n * SP + pw) * C + ci0 + seg * 8) = *(int4*)v;
                }
            }
        }

        float s = 0.f, s2 = 0.f;
        #pragma unroll
        for (int r = 0; r < 16; r++) {
            int pl = ty4 + r * 4;
            int pw = p0 + pl;
            if (pw < SP) {
                float v = bs2f(tile[pl][tx]);
                s += v; s2 += v * v;
            }
        }
        rs[ty4][tx] = s; rq[ty4][tx] = s2;
        __syncthreads();
        if (ty4 == 0) {
            float ts = rs[0][tx] + rs[1][tx] + rs[2][tx] + rs[3][tx];
            float tq = rq[0][tx] + rq[1][tx] + rq[2][tx] + rq[3][tx];
            atomicAdd(&sum1[ci0 + tx], ts);
            atomicAdd(&sq1[ci0 + tx], tq);
        }
    }
}

// ---------------- foldbias (+inline bn1 finalize): w1f = t*scale1, bias1 = t.shift1 ----------------
__global__ void foldbias_kernel(const short* __restrict__ wt,
                                const float* __restrict__ sum, const float* __restrict__ sq,
                                const float* __restrict__ g, const float* __restrict__ b,
                                short* __restrict__ wf, float* __restrict__ bias,
                                int K, float cnt) {
    int f = blockIdx.x;
    float s = 0.f;
    for (int k = threadIdx.x; k < K; k += blockDim.x) {
        float scale, shift;
        bn_fin(sum[k], sq[k], g[k], b[k], cnt, scale, shift);
        float tv = bs2f(wt[(size_t)f * K + k]);
        wf[(size_t)f * K + k] = f2bs(tv * scale);
        s += tv * shift;
    }
    s = block_reduce_sum(s);
    if (threadIdx.x == 0) bias[f] = s;
}

// ---------------- BN stats phase A (h2 only now) ----------------
template <typename T, int VEC>
__global__ __launch_bounds__(256) void bn_sum_kernel(
    const T* __restrict__ src, float* __restrict__ sum, float* __restrict__ sq,
    int C, int spatial, int N, int splits) {
    int c = blockIdx.x;
    int vpc = spatial / VEC;
    int total = N * vpc;
    float s = 0.f, s2 = 0.f;
    for (int v = blockIdx.y * 256 + threadIdx.x; v < total; v += splits * 256) {
        int n = v / vpc;
        int i = v - n * vpc;
        const T* p = src + ((size_t)n * C + c) * spatial + i * VEC;
        short tmp[VEC];
        if (VEC == 8) *(int4*)tmp = *(const int4*)p;
        else          *(int2*)tmp = *(const int2*)p;
        #pragma unroll
        for (int k = 0; k < VEC; k++) { float vv = bs2f(tmp[k]); s += vv; s2 += vv * vv; }
    }
    s = block_reduce_sum(s);
    s2 = block_reduce_sum(s2);
    if (threadIdx.x == 0) {
        atomicAdd(&sum[c], s);
        atomicAdd(&sq[c], s2);
    }
}

// ---------------- dual BN stats: sc (C=1024, sp=196, VEC4) + h1 (C=256, sp=784, VEC8) ----------------
template <int VEC>
__device__ __forceinline__ void bn_sum_body(const bf16* __restrict__ src, int C, int c,
                                            int spatial, int N, int splits,
                                            float* __restrict__ sum, float* __restrict__ sq) {
    int vpc = spatial / VEC;
    int total = N * vpc;
    float s = 0.f, s2 = 0.f;
    for (int v = blockIdx.y * 256 + threadIdx.x; v < total; v += splits * 256) {
        int n = v / vpc;
        int i = v - n * vpc;
        const bf16* p = src + ((size_t)n * C + c) * spatial + i * VEC;
        short tmp[VEC];
        if (VEC == 8) *(int4*)tmp = *(const int4*)p;
        else          *(int2*)tmp = *(const int2*)p;
        #pragma unroll
        for (int k = 0; k < VEC; k++) { float vv = bs2f(tmp[k]); s += vv; s2 += vv * vv; }
    }
    s = block_reduce_sum(s);
    s2 = block_reduce_sum(s2);
    if (threadIdx.x == 0) {
        atomicAdd(&sum[c], s);
        atomicAdd(&sq[c], s2);
    }
}

__global__ __launch_bounds__(256) void bn_sum_dual_kernel(
    const bf16* __restrict__ scv, const bf16* __restrict__ h1,
    float* __restrict__ sumd, float* __restrict__ sqd,
    float* __restrict__ sum2, float* __restrict__ sq2) {
    int cb = blockIdx.x;
    if (cb < 1024) bn_sum_body<4>(scv, 1024, cb, 196, 64, 8, sumd, sqd);
    else           bn_sum_body<8>(h1, 256, cb - 1024, 784, 64, 8, sum2, sq2);
}

// ---------------- affine transpose (bf16, VMEM-wide, +inline bn3 finalize): h2 -> B3t ----------------
__global__ __launch_bounds__(256) void affine_transpose_bf16_kernel(
    const bf16* __restrict__ in,
    const float* __restrict__ sum, const float* __restrict__ sq,
    const float* __restrict__ g, const float* __restrict__ b, float cnt,
    short* __restrict__ Bt, int C, int SP) {
    __shared__ short tile[64][66];
    int n = blockIdx.z;
    int ci0 = blockIdx.y * 64;
    int p0 = blockIdx.x * 64;
    int t = threadIdx.x;

    {
        int p4 = t & 15;
        int cib = t >> 4;
        int p = p0 + p4 * 4;
        bool pok = (p + 3) < SP;          // SP%4==0
        #pragma unroll
        for (int it = 0; it < 4; it++) {
            int ci = cib + it * 16;
            short v[4] = {0, 0, 0, 0};
            if (pok) *(int2*)v = *(const int2*)(in + ((size_t)n * C + ci0 + ci) * SP + p);
            float sc, sh;
            bn_fin(sum[ci0 + ci], sq[ci0 + ci], g[ci0 + ci], b[ci0 + ci], cnt, sc, sh);
            #pragma unroll
            for (int j = 0; j < 4; j++)
                tile[p4 * 4 + j][ci] = f2bs(bs2f(v[j]) * sc + sh);
        }
    }
    __syncthreads();

    {
        int seg = t & 7;
        #pragma unroll
        for (int it = 0; it < 2; it++) {
            int pl = (t >> 3) + it * 32;
            int pw = p0 + pl;
            if (pw < SP) {
                short v[8];
                #pragma unroll
                for (int u = 0; u < 8; u++) v[u] = tile[pl][seg * 8 + u];
                *(int4*)(Bt + ((size_t)n * SP + pw) * C + ci0 + seg * 8) = *(int4*)v;
            }
        }
    }
}

// ---------------- LDS-tiled im2col (+inline bn2 finalize) for conv2 (3x3 s2 p1) ----------------
__global__ __launch_bounds__(256) void im2col_tiled_kernel(
    const bf16* __restrict__ h1,
    const float* __restrict__ sum, const float* __restrict__ sq,
    const float* __restrict__ g, const float* __restrict__ b, float cnt,
    short* __restrict__ B2t) {
    __shared__ short tile[16][784];   // 25 KB
    int cb = blockIdx.x;              // 0..15 (16-channel slab)
    int n  = blockIdx.y;              // 0..63
    int ci0 = cb * 16;
    int t = threadIdx.x;

    for (int v = t; v < 16 * 98; v += 256) {
        int ci = v / 98;
        int i8 = (v - ci * 98) * 8;
        short tmp[8];
        *(int4*)tmp = *(const int4*)(h1 + ((size_t)n * 256 + ci0 + ci) * 784 + i8);
        float sc, sh;
        bn_fin(sum[ci0 + ci], sq[ci0 + ci], g[ci0 + ci], b[ci0 + ci], cnt, sc, sh);
        short ov[8];
        #pragma unroll
        for (int k = 0; k < 8; k++) ov[k] = f2bs(bs2f(tmp[k]) * sc + sh);
        *(int4*)&tile[ci][i8] = *(int4*)ov;
    }
    __syncthreads();

    for (int w = t; w < 196 * 18; w += 256) {
        int p = w / 18, seg = w - p * 18;
        int oh = p / 14, ow = p - oh * 14;
        int kbase = seg * 8;
        short vals[8];
        #pragma unroll
        for (int u = 0; u < 8; u++) {
            int kk = kbase + u;
            int ci_l = kk / 9;
            int rr = kk - ci_l * 9;
            int kh = rr / 3, kw = rr - kh * 3;
            int ih = 2 * oh - 1 + kh;
            int iw = 2 * ow - 1 + kw;
            vals[u] = ((unsigned)ih < 28u && (unsigned)iw < 28u)
                          ? tile[ci_l][ih * 28 + iw] : (short)0;
        }
        *(int4*)(B2t + ((size_t)(n * 196 + p)) * 2304 + ci0 * 9 + kbase) = *(int4*)vals;
    }
}

// ---------------- merged GEMM1 || GEMM4, SAFE 2-phase pipeline ----------------
// G1: verbatim r17 (16 K-tiles, 2-phase). G4 (r19): quad-buffer SUPERBLOCKS —
// process 2 K-tiles per barrier (16 tiles -> 8 iterations, 8 MFMA/iter). Halves
// the exposed-latency events (full-drain barrier cost) while keeping the
// verified-safe sync and the DMA-compatible [64][32] subtile layout.
__global__ __launch_bounds__(256) void gemm14_kernel(
    const short* __restrict__ w1f, const short* __restrict__ dswb,
    const short* __restrict__ B1t,
    const float* __restrict__ alpha1, const float* __restrict__ bias1,
    bf16* __restrict__ h1, bf16* __restrict__ sc) {
    __shared__ short lds[16384];   // 32 KB union
    int blk = blockIdx.x;
    int t = threadIdx.x;
    int w = t >> 6, l = t & 63;
    int r0 = t >> 2;
    int kg = (t & 3) * 8;
    int wbase = w * 512;
    int lm = (l >> 4);
    int lc = l & 15;

    if (blk < 784) {
        // ======== GEMM1: 128x128, M=256, K=512, SP=784, 16 K-tiles, 2-phase ========
        const int SP = 784, M = 256, K = 512;
        int c0 = (blk / 2) * 128;
        int m0 = (blk % 2) * 128;
        int wm = (w >> 1) * 64, wn = (w & 1) * 64;
        size_t rowB0 = c0 + r0;
        size_t rowB1 = c0 + r0 + 64;

        float4v acc[4][4];
        #pragma unroll
        for (int i = 0; i < 4; i++)
            #pragma unroll
            for (int j = 0; j < 4; j++) acc[i][j] = (float4v)0.f;

        gload_lds16(w1f + (size_t)(m0 + r0) * K + kg,      &lds[wbase]);
        gload_lds16(w1f + (size_t)(m0 + r0 + 64) * K + kg, &lds[2048 + wbase]);
        gload_lds16(B1t + rowB0 * K + kg,                  &lds[8192 + wbase]);
        gload_lds16(B1t + rowB1 * K + kg,                  &lds[8192 + 2048 + wbase]);
        __syncthreads();

        for (int it = 0; it < 16; it++) {
            int cur = it & 1;
            int curA = cur * 4096, curB = 8192 + cur * 4096;
            if (it < 15) {
                int nxtA = (cur ^ 1) * 4096, nxtB = 8192 + (cur ^ 1) * 4096;
                int k1 = (it + 1) * 32;
                gload_lds16(w1f + (size_t)(m0 + r0) * K + k1 + kg,      &lds[nxtA + wbase]);
                gload_lds16(w1f + (size_t)(m0 + r0 + 64) * K + k1 + kg, &lds[nxtA + 2048 + wbase]);
                gload_lds16(B1t + rowB0 * K + k1 + kg,                  &lds[nxtB + wbase]);
                gload_lds16(B1t + rowB1 * K + k1 + kg,                  &lds[nxtB + 2048 + wbase]);
            }

            short8 af[4], bfr[4];
            #pragma unroll
            for (int i = 0; i < 4; i++)
                af[i] = *(const short8*)&lds[curA + (wm + i * 16 + lc) * 32 + lm * 8];
            #pragma unroll
            for (int j = 0; j < 4; j++)
                bfr[j] = *(const short8*)&lds[curB + (wn + j * 16 + lc) * 32 + lm * 8];
            #pragma unroll
            for (int i = 0; i < 4; i++)
                #pragma unroll
                for (int j = 0; j < 4; j++)
                    acc[i][j] = __builtin_amdgcn_mfma_f32_16x16x32_bf16(af[i], bfr[j], acc[i][j], 0, 0, 0);
            __syncthreads();
        }

        #pragma unroll
        for (int i = 0; i < 4; i++) {
            #pragma unroll
            for (int r = 0; r < 4; r++) {
                int m = m0 + wm + i * 16 + lm * 4 + r;
                float a = alpha1[m];
                float bia = bias1[m];
                #pragma unroll
                for (int j = 0; j < 4; j++) {
                    int c = c0 + wn + j * 16 + lc;
                    int n = c / SP;
                    int p = c - n * SP;
                    h1[((size_t)n * M + m) * SP + p] = __float2bfloat16((acc[i][j][r] + bia) * a);
                }
            }
        }
    } else {
        // ======== GEMM4: 64x64 + stride-2 remap, M=1024, K=512, 8 superblock iters ====
        // LDS: A ph0 [0,4096) {subtiles 0,2048}, A ph1 [4096,8192); B at 8192 + same.
        const int SP = 196, M = 1024, K = 512;
        int bb = blk - 784;
        int c0 = (bb / 16) * 64;
        int m0 = (bb % 16) * 64;
        int wm = (w >> 1) * 32, wn = (w & 1) * 32;

        int c = c0 + r0;
        int nn = c / 196, pp = c - nn * 196;
        int oh = pp / 14, ow = pp - oh * 14;
        size_t rowB = (size_t)nn * 784 + oh * 56 + ow * 2;

        float4v acc[2][2];
        #pragma unroll
        for (int i = 0; i < 2; i++)
            #pragma unroll
            for (int j = 0; j < 2; j++) acc[i][j] = (float4v)0.f;

        // prologue: stage tiles 0,1 into phase 0
        gload_lds16(dswb + (size_t)(m0 + r0) * K + kg,      &lds[wbase]);
        gload_lds16(dswb + (size_t)(m0 + r0) * K + 32 + kg, &lds[2048 + wbase]);
        gload_lds16(B1t + rowB * K + kg,                    &lds[8192 + wbase]);
        gload_lds16(B1t + rowB * K + 32 + kg,               &lds[8192 + 2048 + wbase]);
        __syncthreads();

        for (int it = 0; it < 8; it++) {
            int ph = it & 1;
            int curA = ph * 4096, curB = 8192 + ph * 4096;
            if (it < 7) {
                int nxtA = (ph ^ 1) * 4096, nxtB = 8192 + (ph ^ 1) * 4096;
                int k1 = (2 * it + 2) * 32;
                gload_lds16(dswb + (size_t)(m0 + r0) * K + k1 + kg,      &lds[nxtA + wbase]);
                gload_lds16(dswb + (size_t)(m0 + r0) * K + k1 + 32 + kg, &lds[nxtA + 2048 + wbase]);
                gload_lds16(B1t + rowB * K + k1 + kg,                    &lds[nxtB + wbase]);
                gload_lds16(B1t + rowB * K + k1 + 32 + kg,               &lds[nxtB + 2048 + wbase]);
            }

            #pragma unroll
            for (int jt = 0; jt < 2; jt++) {
                int a0 = curA + jt * 2048, b0 = curB + jt * 2048;
                short8 af[2], bfr[2];
                #pragma unroll
                for (int i = 0; i < 2; i++)
                    af[i] = *(const short8*)&lds[a0 + (wm + i * 16 + lc) * 32 + lm * 8];
                #pragma unroll
                for (int j = 0; j < 2; j++)
                    bfr[j] = *(const short8*)&lds[b0 + (wn + j * 16 + lc) * 32 + lm * 8];
                #pragma unroll
                for (int i = 0; i < 2; i++)
                    #pragma unroll
                    for (int j = 0; j < 2; j++)
                        acc[i][j] = __builtin_amdgcn_mfma_f32_16x16x32_bf16(af[i], bfr[j], acc[i][j], 0, 0, 0);
            }
            __syncthreads();
        }

        #pragma unroll
        for (int i = 0; i < 2; i++) {
            #pragma unroll
            for (int r = 0; r < 4; r++) {
                int m = m0 + wm + i * 16 + lm * 4 + r;
                #pragma unroll
                for (int j = 0; j < 2; j++) {
                    int cc = c0 + wn + j * 16 + lc;
                    int n = cc / SP;
                    int p = cc - n * SP;
                    sc[((size_t)n * M + m) * SP + p] = __float2bfloat16(acc[i][j][r]);
                }
            }
        }
    }
}

// ---------------- GEMM3: 128x128 tile, SAFE 2-phase dbuf (8 K-tiles) + fused residual ----------------
// Verbatim r18 (passed; neutral perf — epilogue-BW-bound).
__global__ __launch_bounds__(256) void gemm3_kernel(
    const short* __restrict__ A, const short* __restrict__ Bt,
    const float* __restrict__ alpha, float* __restrict__ out,
    int M, int K,
    const bf16* __restrict__ scv,
    const float* __restrict__ fsum, const float* __restrict__ fsq,
    const float* __restrict__ fg, const float* __restrict__ fb, float fcnt) {
    constexpr int SP = 196;
    __shared__ short lds[16384];   // As0 [0,4096) As1 [4096,8192) Bs0 [8192,12288) Bs1 [12288,16384)
    int t = threadIdx.x;
    int c0 = blockIdx.x * 128;
    int m0 = blockIdx.y * 128;
    int w = t >> 6, l = t & 63;
    int wm = (w >> 1) * 64, wn = (w & 1) * 64;

    int r0 = t >> 2;
    int kg = (t & 3) * 8;
    int wbase = w * 512;

    size_t rowB0 = c0 + r0;
    size_t rowB1 = c0 + r0 + 64;

    float4v acc[4][4];
    #pragma unroll
    for (int i = 0; i < 4; i++)
        #pragma unroll
        for (int j = 0; j < 4; j++) acc[i][j] = (float4v)0.f;

    int lm = (l >> 4);
    int lc = l & 15;
    int NT = K / 32;

    gload_lds16(A + (size_t)(m0 + r0) * K + kg,      &lds[wbase]);
    gload_lds16(A + (size_t)(m0 + r0 + 64) * K + kg, &lds[2048 + wbase]);
    gload_lds16(Bt + rowB0 * K + kg,                 &lds[8192 + wbase]);
    gload_lds16(Bt + rowB1 * K + kg,                 &lds[8192 + 2048 + wbase]);
    __syncthreads();

    for (int it = 0; it < NT; it++) {
        int cur = it & 1;
        int curA = cur * 4096, curB = 8192 + cur * 4096;
        if (it < NT - 1) {
            int nxtA = (cur ^ 1) * 4096, nxtB = 8192 + (cur ^ 1) * 4096;
            int k1 = (it + 1) * 32;
            gload_lds16(A + (size_t)(m0 + r0) * K + k1 + kg,      &lds[nxtA + wbase]);
            gload_lds16(A + (size_t)(m0 + r0 + 64) * K + k1 + kg, &lds[nxtA + 2048 + wbase]);
            gload_lds16(Bt + rowB0 * K + k1 + kg,                 &lds[nxtB + wbase]);
            gload_lds16(Bt + rowB1 * K + k1 + kg,                 &lds[nxtB + 2048 + wbase]);
        }

        short8 af[4], bfr[4];
        #pragma unroll
        for (int i = 0; i < 4; i++)
            af[i] = *(const short8*)&lds[curA + (wm + i * 16 + lc) * 32 + lm * 8];
        #pragma unroll
        for (int j = 0; j < 4; j++)
            bfr[j] = *(const short8*)&lds[curB + (wn + j * 16 + lc) * 32 + lm * 8];
        #pragma unroll
        for (int i = 0; i < 4; i++)
            #pragma unroll
            for (int j = 0; j < 4; j++)
                acc[i][j] = __builtin_amdgcn_mfma_f32_16x16x32_bf16(af[i], bfr[j], acc[i][j], 0, 0, 0);
        __syncthreads();
    }

    #pragma unroll
    for (int i = 0; i < 4; i++) {
        #pragma unroll
        for (int r = 0; r < 4; r++) {
            int m = m0 + wm + i * 16 + lm * 4 + r;
            float a = alpha[m];
            float fsc, fsh;
            bn_fin(fsum[m], fsq[m], fg[m], fb[m], fcnt, fsc, fsh);
            #pragma unroll
            for (int j = 0; j < 4; j++) {
                int c = c0 + wn + j * 16 + lc;
                int n = c / SP;
                int p = c - n * SP;
                size_t idx = ((size_t)n * M + m) * SP + p;
                float v = acc[i][j][r] * a + toF(scv[idx]) * fsc + fsh;
                out[idx] = v;
            }
        }
    }
}

// ---------------- GEMM2: 64x64 tile, quad-buffer superblocks (72 tiles -> 36 iters) ----------------
// r19: 2 K-tiles per barrier iteration. LDS 32KB: A ph0 [0,4096) {subtiles 0,2048},
// A ph1 [4096,8192); B at 8192 + same. Grid-limited ~3 blocks/CU so 32KB is free.
__global__ __launch_bounds__(256) void gemm2_kernel(
    const short* __restrict__ A, const short* __restrict__ Bt,
    const float* __restrict__ alpha, bf16* __restrict__ out,
    int M, int K) {
    constexpr int SP = 196;
    __shared__ short lds[16384];
    int t = threadIdx.x;
    int c0 = blockIdx.x * 64;
    int m0 = blockIdx.y * 64;
    int w = t >> 6, l = t & 63;
    int wm = (w >> 1) * 32, wn = (w & 1) * 32;

    int r0 = t >> 2;          // 0..63
    int kg = (t & 3) * 8;     // 0,8,16,24
    int wbase = w * 512;

    float4v acc[2][2];
    #pragma unroll
    for (int i = 0; i < 2; i++)
        #pragma unroll
        for (int j = 0; j < 2; j++) acc[i][j] = (float4v)0.f;

    int lm = (l >> 4);
    int lc = l & 15;
    int NI = K / 64;          // 36 superblock iterations

    // prologue: stage tiles 0,1 into phase 0
    gload_lds16(A + (size_t)(m0 + r0) * K + kg,       &lds[wbase]);
    gload_lds16(A + (size_t)(m0 + r0) * K + 32 + kg,  &lds[2048 + wbase]);
    gload_lds16(Bt + (size_t)(c0 + r0) * K + kg,      &lds[8192 + wbase]);
    gload_lds16(Bt + (size_t)(c0 + r0) * K + 32 + kg, &lds[8192 + 2048 + wbase]);
    __syncthreads();

    for (int it = 0; it < NI; it++) {
        int ph = it & 1;
        int curA = ph * 4096, curB = 8192 + ph * 4096;
        if (it < NI - 1) {
            int nxtA = (ph ^ 1) * 4096, nxtB = 8192 + (ph ^ 1) * 4096;
            int k1 = (2 * it + 2) * 32;
            gload_lds16(A + (size_t)(m0 + r0) * K + k1 + kg,       &lds[nxtA + wbase]);
            gload_lds16(A + (size_t)(m0 + r0) * K + k1 + 32 + kg,  &lds[nxtA + 2048 + wbase]);
            gload_lds16(Bt + (size_t)(c0 + r0) * K + k1 + kg,      &lds[nxtB + wbase]);
            gload_lds16(Bt + (size_t)(c0 + r0) * K + k1 + 32 + kg, &lds[nxtB + 2048 + wbase]);
        }

        #pragma unroll
        for (int jt = 0; jt < 2; jt++) {
            int a0 = curA + jt * 2048, b0 = curB + jt * 2048;
            short8 af[2], bfr[2];
            #pragma unroll
            for (int i = 0; i < 2; i++)
                af[i] = *(const short8*)&lds[a0 + (wm + i * 16 + lc) * 32 + lm * 8];
            #pragma unroll
            for (int j = 0; j < 2; j++)
                bfr[j] = *(const short8*)&lds[b0 + (wn + j * 16 + lc) * 32 + lm * 8];
            #pragma unroll
            for (int i = 0; i < 2; i++)
                #pragma unroll
                for (int j = 0; j < 2; j++)
                    acc[i][j] = __builtin_amdgcn_mfma_f32_16x16x32_bf16(af[i], bfr[j], acc[i][j], 0, 0, 0);
        }
        __syncthreads();
    }

    #pragma unroll
    for (int i = 0; i < 2; i++) {
        #pragma unroll
        for (int r = 0; r < 4; r++) {
            int m = m0 + wm + i * 16 + lm * 4 + r;
            float a = alpha[m];
            #pragma unroll
            for (int j = 0; j < 2; j++) {
                int c = c0 + wn + j * 16 + lc;
                int n = c / SP;
                int p = c - n * SP;
                out[((size_t)n * M + m) * SP + p] = __float2bfloat16(acc[i][j][r] * a);
            }
        }
    }
}

extern "C" void kernel_launch(void* const* d_in, const int* in_sizes, int n_in,
                              void* d_out, int out_size, void* d_ws, size_t ws_size,
                              hipStream_t stream) {
    const float* x      = (const float*)d_in[0];   // (64,512,28,28)
    const float* bn1_g  = (const float*)d_in[1];
    const float* bn1_b  = (const float*)d_in[2];
    const float* w1     = (const float*)d_in[3];   // (256,512,1,1)
    const float* bn2_g  = (const float*)d_in[4];
    const float* bn2_b  = (const float*)d_in[5];
    const float* w2     = (const float*)d_in[6];   // (256,256,3,3)
    const float* bn3_g  = (const float*)d_in[7];
    const float* bn3_b  = (const float*)d_in[8];
    const float* w3     = (const float*)d_in[9];   // (1024,256,1,1)
    const float* ds_w   = (const float*)d_in[10];  // (1024,512,1,1) NOT ternarized
    const float* dbn_g  = (const float*)d_in[11];
    const float* dbn_b  = (const float*)d_in[12];
    float* out = (float*)d_out;

    const int N = 64, C1 = 512, C2 = 256, C3 = 1024;
    const int SP1 = 784, SP2 = 196;
    const int NT1 = N * SP1;   // 50176
    const int NT2 = N * SP2;   // 12544

    // ---- workspace layout ----
    char* wsb = (char*)d_ws;
    size_t off = 0;
    auto alloc = [&](size_t bytes) { char* p = wsb + off; off += (bytes + 255) & ~(size_t)255; return p; };

    char* pool = alloc((size_t)NT2 * 2304 * 2);   // 57.8 MB: B1t (51.4) / B2t (57.8) / B3t (6.4) time-share
    short* B1t = (short*)pool;                    // raw bf16(x)^T; live until gemm14
    short* B2t = (short*)pool;                    // created by im2col AFTER gemm14
    short* B3t = (short*)pool;                    // created after B2t is dead
    bf16*  sc  = (bf16*)alloc((size_t)N * C3 * SP2 * 2);  // 25.7 MB, own region

    bf16* h1 = (bf16*)alloc((size_t)N * C2 * SP1 * 2);
    bf16* h2 = (bf16*)alloc((size_t)N * C2 * SP2 * 2);
    short* w1t  = (short*)alloc((size_t)C2 * C1 * 2);
    short* w1f  = (short*)alloc((size_t)C2 * C1 * 2);   // scale-folded w1
    short* w2t  = (short*)alloc((size_t)C2 * C2 * 9 * 2);
    short* w3t  = (short*)alloc((size_t)C3 * C2 * 2);
    short* dswb = (short*)alloc((size_t)C3 * C1 * 2);
    float* alpha1 = (float*)alloc(C2 * 4);
    float* alpha2 = (float*)alloc(C2 * 4);
    float* alpha3 = (float*)alloc(C3 * 4);
    float* bias1  = (float*)alloc(C2 * 4);
    float* acc_base = (float*)alloc((size_t)(C1 + C2 + C2 + C3) * 2 * 4);
    float* sum1 = acc_base;            float* sq1 = sum1 + C1;
    float* sum2 = sq1 + C1;            float* sq2 = sum2 + C2;
    float* sum3 = sq2 + C2;            float* sq3 = sum3 + C2;
    float* sumd = sq3 + C2;            float* sqd = sumd + C3;
    (void)ws_size; (void)in_sizes; (void)n_in; (void)out_size;

    // 1) zero BN accumulators
    hipMemsetAsync(acc_base, 0, (size_t)(C1 + C2 + C2 + C3) * 2 * 4, stream);

    // 2) merged prep: weights (ternarize+cast) || stats_transpose (x -> B1t + bn1 stats)
    prep_kernel<<<10240, 256, 0, stream>>>(w1, w2, w3, ds_w, w1t, w2t, w3t, dswb,
                                           alpha1, alpha2, alpha3, x, B1t, sum1, sq1);

    // 3) foldbias (+inline bn1 finalize): w1f, bias1
    foldbias_kernel<<<C2, 256, 0, stream>>>(w1t, sum1, sq1, bn1_g, bn1_b,
                                            w1f, bias1, C1, (float)(N * SP1));

    // 4) merged GEMM1 || GEMM4 (2-phase / quad-superblock pipelines): h1, sc
    gemm14_kernel<<<3920, 256, 0, stream>>>(w1f, dswb, B1t, alpha1, bias1, h1, sc);

    // 5) dual BN stats: sc -> sumd/sqd, h1 -> sum2/sq2
    bn_sum_dual_kernel<<<dim3(C3 + C2, 8), 256, 0, stream>>>(
        sc, h1, sumd, sqd, sum2, sq2);

    // 6) im2col (+inline bn2 finalize) -> B2t (overwrites pool; B1t dead)
    im2col_tiled_kernel<<<dim3(16, 64), 256, 0, stream>>>(
        h1, sum2, sq2, bn2_g, bn2_b, (float)(N * SP1), B2t);

    // 7) GEMM2 (64x64, quad-superblock pipeline): h2 = alpha2 * (w2t . B2t^T)  M=256 K=2304
    gemm2_kernel<<<dim3(NT2 / 64, C2 / 64), 256, 0, stream>>>(
        w2t, B2t, alpha2, h2, C2, C2 * 9);

    // 8) bn3 stats on h2
    bn_sum_kernel<bf16, 4><<<dim3(C2, 4), 256, 0, stream>>>(h2, sum3, sq3, C2, SP2, N, 4);

    // 9) B3t = bn3(h2)^T (+inline bn3 finalize)
    {
        dim3 grid((SP2 + 63) / 64, C2 / 64, N);
        affine_transpose_bf16_kernel<<<grid, 256, 0, stream>>>(
            h2, sum3, sq3, bn3_g, bn3_b, (float)(N * SP2), B3t, C2, SP2);
    }

    // 10) GEMM3 (safe 2-phase dbuf, fused residual + inline ds-bn finalize):
    //     out = alpha3*(w3t . B3t^T) + sc*scaled + shiftd
    gemm3_kernel<<<dim3(NT2 / 128, C3 / 128), 256, 0, stream>>>(
        w3t, B3t, alpha3, out, C3, C2,
        sc, sumd, sqd, dbn_g, dbn_b, (float)(N * SP2));
}